// Round 1
// baseline (1764.080 us; speedup 1.0000x reference)
//
#include <hip/hip_runtime.h>

// ---------------------------------------------------------------------------
// GCN forward, fp32 baseline:
//   h1 = relu(segsum(ew * (x@W1)[src] -> dst) + b1)    128 -> 128
//   h2 = relu(segsum(ew * (h1@W2)[src] -> dst) + b2)   128 -> 64
// ---------------------------------------------------------------------------

#define K_FEAT 128

// C[M,N] = A[M,K=128] * W[K,N] ; BM=BN=BK=64, 4x4 per thread, 256 threads.
__global__ __launch_bounds__(256) void gemm64_kernel(const float* __restrict__ A,
                                                     const float* __restrict__ W,
                                                     float* __restrict__ C,
                                                     int M, int N) {
    const int BM = 64, BN = 64, BK = 64, K = K_FEAT;
    __shared__ float At[BK][BM + 4];   // transposed A tile, padded
    __shared__ float Wt[BK][BN + 4];
    const int m0 = blockIdx.x * BM;
    const int n0 = blockIdx.y * BN;
    const int tid = threadIdx.x;
    const int tx = tid & 15, ty = tid >> 4;
    const int r0 = ty * 4, c0 = tx * 4;
    float acc[4][4] = {};

    for (int k0 = 0; k0 < K; k0 += BK) {
        // Stage A tile (BM x BK) transposed into LDS. float4 along k.
        #pragma unroll
        for (int it = 0; it < (BM * BK) / (256 * 4); ++it) {
            int idx = tid * 4 + it * 1024;
            int r = idx / BK, k = idx & (BK - 1);
            int row = m0 + r;
            float4 v = make_float4(0.f, 0.f, 0.f, 0.f);
            if (row < M) v = *(const float4*)(A + (size_t)row * K + k0 + k);
            At[k + 0][r] = v.x;
            At[k + 1][r] = v.y;
            At[k + 2][r] = v.z;
            At[k + 3][r] = v.w;
        }
        // Stage W tile (BK x BN).
        #pragma unroll
        for (int it = 0; it < (BK * BN) / (256 * 4); ++it) {
            int idx = tid * 4 + it * 1024;
            int k = idx / BN, c = idx & (BN - 1);
            float4 v = *(const float4*)(W + (size_t)(k0 + k) * N + n0 + c);
            Wt[k][c + 0] = v.x;
            Wt[k][c + 1] = v.y;
            Wt[k][c + 2] = v.z;
            Wt[k][c + 3] = v.w;
        }
        __syncthreads();
        #pragma unroll 8
        for (int k = 0; k < BK; ++k) {
            float a[4], w[4];
            *(float4*)a = *(const float4*)&At[k][r0];
            *(float4*)w = *(const float4*)&Wt[k][c0];
            #pragma unroll
            for (int i = 0; i < 4; ++i)
                #pragma unroll
                for (int j = 0; j < 4; ++j)
                    acc[i][j] = fmaf(a[i], w[j], acc[i][j]);
        }
        __syncthreads();
    }
    #pragma unroll
    for (int i = 0; i < 4; ++i) {
        int row = m0 + r0 + i;
        if (row < M)
            *(float4*)(C + (size_t)row * N + n0 + c0) =
                make_float4(acc[i][0], acc[i][1], acc[i][2], acc[i][3]);
    }
}

// One wave per edge: gather support[src], scale by ew, atomic-add into agg[dst].
template <int F>
__global__ __launch_bounds__(256) void scatter_kernel(const float* __restrict__ sup,
                                                      const int* __restrict__ src,
                                                      const int* __restrict__ dst,
                                                      const float* __restrict__ ew,
                                                      float* __restrict__ agg, int E) {
    int gid = blockIdx.x * 256 + threadIdx.x;
    int e = gid >> 6;
    int lane = gid & 63;
    if (e >= E) return;
    int s = src[e];
    int d = dst[e];
    float w = ew[e];
    if (F == 128) {
        float2 v = *(const float2*)(sup + (size_t)s * 128 + lane * 2);
        unsafeAtomicAdd(agg + (size_t)d * 128 + lane * 2 + 0, v.x * w);
        unsafeAtomicAdd(agg + (size_t)d * 128 + lane * 2 + 1, v.y * w);
    } else {  // F == 64
        float v = sup[(size_t)s * 64 + lane];
        unsafeAtomicAdd(agg + (size_t)d * 64 + lane, v * w);
    }
}

// out = relu(agg + b[col]) elementwise, float4-vectorized. F power of two.
template <int F>
__global__ __launch_bounds__(256) void bias_relu_kernel(const float* __restrict__ agg,
                                                        const float* __restrict__ b,
                                                        float* __restrict__ out,
                                                        int total4) {
    int i = blockIdx.x * 256 + threadIdx.x;
    if (i >= total4) return;
    float4 v = ((const float4*)agg)[i];
    int col = (i * 4) & (F - 1);
    v.x = fmaxf(v.x + b[col + 0], 0.f);
    v.y = fmaxf(v.y + b[col + 1], 0.f);
    v.z = fmaxf(v.z + b[col + 2], 0.f);
    v.w = fmaxf(v.w + b[col + 3], 0.f);
    ((float4*)out)[i] = v;
}

extern "C" void kernel_launch(void* const* d_in, const int* in_sizes, int n_in,
                              void* d_out, int out_size, void* d_ws, size_t ws_size,
                              hipStream_t stream) {
    const float* x  = (const float*)d_in[0];
    const int*   ei = (const int*)d_in[1];   // [2, E] int32
    const float* ew = (const float*)d_in[2];
    const float* W1 = (const float*)d_in[3];
    const float* b1 = (const float*)d_in[4];
    const float* W2 = (const float*)d_in[5];
    const float* b2 = (const float*)d_in[6];
    float* out = (float*)d_out;

    const int N = in_sizes[0] / K_FEAT;  // 100000 nodes
    const int E = in_sizes[2];           // 1600000 edges
    const int* src = ei;
    const int* dst = ei + E;

    // Workspace layout (reused):
    //   S1   [N*128] : support1, then h1 (in place of support1)
    //   AGG1 [N*128] : layer-1 aggregate, then support2 (reuses AGG1)
    // agg2 accumulates directly in d_out. Total ws: N*128*4*2 = 102.4 MB.
    char* ws = (char*)d_ws;
    float* S1   = (float*)(ws);
    float* AGG1 = (float*)(ws + (size_t)N * 128 * sizeof(float));
    float* H1   = S1;    // h1 overwrites support1
    float* S2   = AGG1;  // support2 overwrites agg1

    // Zero the accumulators (harness does not re-poison between replays).
    hipMemsetAsync(AGG1, 0, (size_t)N * 128 * sizeof(float), stream);
    hipMemsetAsync(out, 0, (size_t)N * 64 * sizeof(float), stream);

    // ---- layer 1 ----
    dim3 g1((N + 63) / 64, 2);
    gemm64_kernel<<<g1, 256, 0, stream>>>(x, W1, S1, N, 128);          // S1 = x@W1
    scatter_kernel<128><<<(E + 3) / 4, 256, 0, stream>>>(S1, src, dst, ew, AGG1, E);
    bias_relu_kernel<128><<<((N * 32) + 255) / 256, 256, 0, stream>>>(AGG1, b1, H1, N * 32);

    // ---- layer 2 ----
    dim3 g2((N + 63) / 64, 1);
    gemm64_kernel<<<g2, 256, 0, stream>>>(H1, W2, S2, N, 64);          // S2 = h1@W2
    scatter_kernel<64><<<(E + 3) / 4, 256, 0, stream>>>(S2, src, dst, ew, out, E);
    bias_relu_kernel<64><<<((N * 16) + 255) / 256, 256, 0, stream>>>(out, b2, out, N * 16);
}

// Round 2
// 511.026 us; speedup vs baseline: 3.4520x; 3.4520x over previous
//
#include <hip/hip_runtime.h>

// ---------------------------------------------------------------------------
// GCN forward, CSR gather-side aggregation (no fp32 atomics in hot path):
//   h1 = relu(segsum(ew * (x@W1)[src] -> dst) + b1)    128 -> 128
//   h2 = relu(segsum(ew * (h1@W2)[src] -> dst) + b2)   128 -> 64
// CSR (edges sorted by dst) built on-device every launch.
// ---------------------------------------------------------------------------

#define K_FEAT 128

// C[M,N] = A[M,K=128] * W[K,N] ; BM=BN=BK=64, 4x4 per thread, 256 threads.
__global__ __launch_bounds__(256) void gemm64_kernel(const float* __restrict__ A,
                                                     const float* __restrict__ W,
                                                     float* __restrict__ C,
                                                     int M, int N) {
    const int BM = 64, BN = 64, BK = 64, K = K_FEAT;
    __shared__ float At[BK][BM + 4];
    __shared__ float Wt[BK][BN + 4];
    const int m0 = blockIdx.x * BM;
    const int n0 = blockIdx.y * BN;
    const int tid = threadIdx.x;
    const int tx = tid & 15, ty = tid >> 4;
    const int r0 = ty * 4, c0 = tx * 4;
    float acc[4][4] = {};

    for (int k0 = 0; k0 < K; k0 += BK) {
        #pragma unroll
        for (int it = 0; it < (BM * BK) / (256 * 4); ++it) {
            int idx = tid * 4 + it * 1024;
            int r = idx / BK, k = idx & (BK - 1);
            int row = m0 + r;
            float4 v = make_float4(0.f, 0.f, 0.f, 0.f);
            if (row < M) v = *(const float4*)(A + (size_t)row * K + k0 + k);
            At[k + 0][r] = v.x;
            At[k + 1][r] = v.y;
            At[k + 2][r] = v.z;
            At[k + 3][r] = v.w;
        }
        #pragma unroll
        for (int it = 0; it < (BK * BN) / (256 * 4); ++it) {
            int idx = tid * 4 + it * 1024;
            int k = idx / BN, c = idx & (BN - 1);
            float4 v = *(const float4*)(W + (size_t)(k0 + k) * N + n0 + c);
            Wt[k][c + 0] = v.x;
            Wt[k][c + 1] = v.y;
            Wt[k][c + 2] = v.z;
            Wt[k][c + 3] = v.w;
        }
        __syncthreads();
        #pragma unroll 8
        for (int k = 0; k < BK; ++k) {
            float a[4], w[4];
            *(float4*)a = *(const float4*)&At[k][r0];
            *(float4*)w = *(const float4*)&Wt[k][c0];
            #pragma unroll
            for (int i = 0; i < 4; ++i)
                #pragma unroll
                for (int j = 0; j < 4; ++j)
                    acc[i][j] = fmaf(a[i], w[j], acc[i][j]);
        }
        __syncthreads();
    }
    #pragma unroll
    for (int i = 0; i < 4; ++i) {
        int row = m0 + r0 + i;
        if (row < M)
            *(float4*)(C + (size_t)row * N + n0 + c0) =
                make_float4(acc[i][0], acc[i][1], acc[i][2], acc[i][3]);
    }
}

// ---- CSR build -------------------------------------------------------------

__global__ __launch_bounds__(256) void hist_kernel(const int* __restrict__ dst,
                                                   int* __restrict__ deg, int E) {
    int i = blockIdx.x * 256 + threadIdx.x;
    if (i < E) atomicAdd(&deg[dst[i]], 1);
}

// Per-block exclusive scan of deg -> rowptr; block totals -> bsum.
__global__ __launch_bounds__(256) void scan_block_kernel(const int* __restrict__ deg,
                                                         int* __restrict__ rowptr,
                                                         int* __restrict__ bsum, int N) {
    __shared__ int s[256];
    int tid = threadIdx.x;
    int i = blockIdx.x * 256 + tid;
    int v = (i < N) ? deg[i] : 0;
    s[tid] = v;
    __syncthreads();
    #pragma unroll
    for (int off = 1; off < 256; off <<= 1) {
        int t = (tid >= off) ? s[tid - off] : 0;
        __syncthreads();
        s[tid] += t;
        __syncthreads();
    }
    if (i < N) rowptr[i] = s[tid] - v;  // exclusive
    if (tid == 255) bsum[blockIdx.x] = s[255];
}

// Single-block exclusive scan of bsum[NB] (NB <= 512).
__global__ __launch_bounds__(512) void scan_sums_kernel(int* __restrict__ bsum, int NB) {
    __shared__ int s[512];
    int tid = threadIdx.x;
    int v = (tid < NB) ? bsum[tid] : 0;
    s[tid] = v;
    __syncthreads();
    #pragma unroll
    for (int off = 1; off < 512; off <<= 1) {
        int t = (tid >= off) ? s[tid - off] : 0;
        __syncthreads();
        s[tid] += t;
        __syncthreads();
    }
    if (tid < NB) bsum[tid] = s[tid] - v;
}

__global__ __launch_bounds__(256) void add_off_kernel(int* __restrict__ rowptr,
                                                      const int* __restrict__ bsum,
                                                      int N, int E) {
    int i = blockIdx.x * 256 + threadIdx.x;
    if (i < N) rowptr[i] += bsum[i >> 8];
    if (i == 0) rowptr[N] = E;
}

__global__ __launch_bounds__(256) void fill_kernel(const int* __restrict__ src,
                                                   const int* __restrict__ dst,
                                                   const float* __restrict__ ew,
                                                   const int* __restrict__ rowptr,
                                                   int* __restrict__ cursor,
                                                   int* __restrict__ csr_src,
                                                   float* __restrict__ csr_w, int E) {
    int e = blockIdx.x * 256 + threadIdx.x;
    if (e >= E) return;
    int d = dst[e];
    int pos = rowptr[d] + atomicAdd(&cursor[d], 1);
    csr_src[pos] = src[e];
    csr_w[pos] = ew[e];
}

// ---- Aggregation: one wave per dst node, fused bias+ReLU -------------------

template <int F>
__global__ __launch_bounds__(256) void agg_kernel(const float* __restrict__ sup,
                                                  const int* __restrict__ rowptr,
                                                  const int* __restrict__ csr_src,
                                                  const float* __restrict__ csr_w,
                                                  const float* __restrict__ bias,
                                                  float* __restrict__ out, int N) {
    int wid = (blockIdx.x * 256 + threadIdx.x) >> 6;
    int lane = threadIdx.x & 63;
    if (wid >= N) return;
    int start = rowptr[wid];
    int end = rowptr[wid + 1];

    if (F == 128) {
        float2 acc = make_float2(0.f, 0.f);
        for (int c = start; c < end; c += 64) {
            int nn = min(64, end - c);
            int s = 0;
            float w = 0.f;
            if (lane < nn) { s = csr_src[c + lane]; w = csr_w[c + lane]; }
            for (int j = 0; j < nn; ++j) {
                int sj = __shfl(s, j);
                float wj = __shfl(w, j);
                float2 v = *(const float2*)(sup + (size_t)sj * 128 + lane * 2);
                acc.x = fmaf(v.x, wj, acc.x);
                acc.y = fmaf(v.y, wj, acc.y);
            }
        }
        float2 b = *(const float2*)(bias + lane * 2);
        acc.x = fmaxf(acc.x + b.x, 0.f);
        acc.y = fmaxf(acc.y + b.y, 0.f);
        *(float2*)(out + (size_t)wid * 128 + lane * 2) = acc;
    } else {  // F == 64
        float acc = 0.f;
        for (int c = start; c < end; c += 64) {
            int nn = min(64, end - c);
            int s = 0;
            float w = 0.f;
            if (lane < nn) { s = csr_src[c + lane]; w = csr_w[c + lane]; }
            for (int j = 0; j < nn; ++j) {
                int sj = __shfl(s, j);
                float wj = __shfl(w, j);
                float v = sup[(size_t)sj * 64 + lane];
                acc = fmaf(v, wj, acc);
            }
        }
        out[(size_t)wid * 64 + lane] = fmaxf(acc + bias[lane], 0.f);
    }
}

extern "C" void kernel_launch(void* const* d_in, const int* in_sizes, int n_in,
                              void* d_out, int out_size, void* d_ws, size_t ws_size,
                              hipStream_t stream) {
    const float* x  = (const float*)d_in[0];
    const int*   ei = (const int*)d_in[1];
    const float* ew = (const float*)d_in[2];
    const float* W1 = (const float*)d_in[3];
    const float* b1 = (const float*)d_in[4];
    const float* W2 = (const float*)d_in[5];
    const float* b2 = (const float*)d_in[6];
    float* out = (float*)d_out;

    const int N = in_sizes[0] / K_FEAT;  // 100000
    const int E = in_sizes[2];           // 1600000
    const int* src = ei;
    const int* dst = ei + E;
    const int NB = (N + 255) / 256;      // scan blocks (<=512 required)

    // Workspace layout:
    //   S   [N*128] f32 : support1, later support2 (overwrites)
    //   H1  [N*128] f32 : relu(agg1 + b1)
    //   csr_src [E] int, csr_w [E] f32
    //   rowptr [N+1] int, deg+cursor [2N] int, bsum [512] int
    char* ws = (char*)d_ws;
    size_t o = 0;
    float* S       = (float*)(ws + o); o += (size_t)N * 128 * sizeof(float);
    float* H1      = (float*)(ws + o); o += (size_t)N * 128 * sizeof(float);
    int*   csr_src = (int*)  (ws + o); o += (size_t)E * sizeof(int);
    float* csr_w   = (float*)(ws + o); o += (size_t)E * sizeof(float);
    int*   rowptr  = (int*)  (ws + o); o += (size_t)(N + 1) * sizeof(int);
    int*   degcur  = (int*)  (ws + o); o += (size_t)2 * N * sizeof(int);
    int*   bsum    = (int*)  (ws + o); o += 512 * sizeof(int);
    int*   deg    = degcur;
    int*   cursor = degcur + N;

    // ---- CSR build (depends only on edge_index) ----
    hipMemsetAsync(degcur, 0, (size_t)2 * N * sizeof(int), stream);
    hist_kernel<<<(E + 255) / 256, 256, 0, stream>>>(dst, deg, E);
    scan_block_kernel<<<NB, 256, 0, stream>>>(deg, rowptr, bsum, N);
    scan_sums_kernel<<<1, 512, 0, stream>>>(bsum, NB);
    add_off_kernel<<<NB, 256, 0, stream>>>(rowptr, bsum, N, E);
    fill_kernel<<<(E + 255) / 256, 256, 0, stream>>>(src, dst, ew, rowptr, cursor,
                                                     csr_src, csr_w, E);

    // ---- layer 1: S = x@W1 ; H1 = relu(agg(S) + b1) ----
    dim3 g1((N + 63) / 64, 2);
    gemm64_kernel<<<g1, 256, 0, stream>>>(x, W1, S, N, 128);
    agg_kernel<128><<<(N + 3) / 4, 256, 0, stream>>>(S, rowptr, csr_src, csr_w, b1, H1, N);

    // ---- layer 2: S = H1@W2 ; out = relu(agg(S) + b2) ----
    dim3 g2((N + 63) / 64, 1);
    gemm64_kernel<<<g2, 256, 0, stream>>>(H1, W2, S, N, 64);
    agg_kernel<64><<<(N + 3) / 4, 256, 0, stream>>>(S, rowptr, csr_src, csr_w, b2, out, N);
}

// Round 3
// 404.180 us; speedup vs baseline: 4.3646x; 1.2644x over previous
//
#include <hip/hip_runtime.h>

// ---------------------------------------------------------------------------
// GCN forward. CSR gather-side aggregation + bf16 MFMA GEMMs.
//   h1 = relu(segsum(ew * (x@W1)[src] -> dst) + b1)    128 -> 128
//   h2 = relu(segsum(ew * (h1@W2)[src] -> dst) + b2)   128 -> 64
// ---------------------------------------------------------------------------

typedef __attribute__((ext_vector_type(8))) short bf16x8;
typedef __attribute__((ext_vector_type(4))) float f32x4;

__device__ __forceinline__ ushort f2bf(float f) {
    uint u = __float_as_uint(f);
    u += 0x7fff + ((u >> 16) & 1);   // round-to-nearest-even
    return (ushort)(u >> 16);
}
__device__ __forceinline__ float bf_lo(uint bits) { return __uint_as_float(bits << 16); }
__device__ __forceinline__ float bf_hi(uint bits) { return __uint_as_float(bits & 0xffff0000u); }

// ---- GEMM: C[M,BN](bf16) = A[M,128] * W[128,BN],  A f32 or bf16 ------------
// 256 threads, block tile 128 x BN. A staged in LDS (bf16, XOR-swizzled);
// W fragments loaded from global (W is <=64KB, L2-hot). fp32 accumulate.
template <int BN, bool ABF16>
__global__ __launch_bounds__(256) void gemm_mfma(const void* __restrict__ Av,
                                                 const float* __restrict__ W,
                                                 ushort* __restrict__ C, int M) {
    __shared__ ushort As[128 * 128];   // [row][k] bf16, byte ^= (row&7)<<4
    const int tid = threadIdx.x;
    const int m0 = blockIdx.x * 128;

    // stage A: 2048 chunks of 8 elems (16B), 8 per thread
    #pragma unroll
    for (int it = 0; it < 8; ++it) {
        int c = tid + it * 256;
        int r = c >> 4;
        int k8 = (c & 15) << 3;
        int row = m0 + r;
        uint4 w4 = make_uint4(0u, 0u, 0u, 0u);
        if (row < M) {
            if (ABF16) {
                w4 = *(const uint4*)((const ushort*)Av + (size_t)row * 128 + k8);
            } else {
                const float* A = (const float*)Av;
                float4 v0 = *(const float4*)(A + (size_t)row * 128 + k8);
                float4 v1 = *(const float4*)(A + (size_t)row * 128 + k8 + 4);
                w4.x = (uint)f2bf(v0.x) | ((uint)f2bf(v0.y) << 16);
                w4.y = (uint)f2bf(v0.z) | ((uint)f2bf(v0.w) << 16);
                w4.z = (uint)f2bf(v1.x) | ((uint)f2bf(v1.y) << 16);
                w4.w = (uint)f2bf(v1.z) | ((uint)f2bf(v1.w) << 16);
            }
        }
        int byte = (r * 256 + k8 * 2) ^ ((r & 7) << 4);
        *(uint4*)((char*)As + byte) = w4;
    }
    __syncthreads();

    const int wid = tid >> 6, lane = tid & 63;
    constexpr int IF = (BN == 128) ? 4 : 2;          // 16-row frags per wave
    const int wy = (BN == 128) ? (wid >> 1) : wid;
    const int wx = (BN == 128) ? (wid & 1) : 0;
    const int rb = wy * 16 * IF;                      // wave row base
    const int cb = wx * 64;                           // wave col base
    const int ln = lane & 15;
    const int kg = lane >> 4;

    f32x4 acc[IF][4];
    #pragma unroll
    for (int i = 0; i < IF; ++i)
        #pragma unroll
        for (int j = 0; j < 4; ++j) acc[i][j] = (f32x4){0.f, 0.f, 0.f, 0.f};

    #pragma unroll
    for (int s = 0; s < 4; ++s) {
        // B frags from global f32 W: lane holds B[k=s*32+kg*8+jj][n=cb+j*16+ln]
        bf16x8 b[4];
        #pragma unroll
        for (int j = 0; j < 4; ++j) {
            int n = cb + j * 16 + ln;
            int kb = s * 32 + kg * 8;
            #pragma unroll
            for (int jj = 0; jj < 8; ++jj)
                b[j][jj] = (short)f2bf(W[(size_t)(kb + jj) * BN + n]);
        }
        // A frags from LDS: lane holds A[r=rb+i*16+ln][k=s*32+kg*8+jj]
        bf16x8 a[IF];
        #pragma unroll
        for (int i = 0; i < IF; ++i) {
            int r = rb + i * 16 + ln;
            int byte = (r * 256 + s * 64 + kg * 16) ^ ((r & 7) << 4);
            a[i] = *(const bf16x8*)((const char*)As + byte);
        }
        #pragma unroll
        for (int i = 0; i < IF; ++i)
            #pragma unroll
            for (int j = 0; j < 4; ++j)
                acc[i][j] = __builtin_amdgcn_mfma_f32_16x16x32_bf16(a[i], b[j], acc[i][j], 0, 0, 0);
    }

    // C/D layout: col = cb + j*16 + (lane&15), row = rb + i*16 + (lane>>4)*4 + q
    #pragma unroll
    for (int i = 0; i < IF; ++i)
        #pragma unroll
        for (int q = 0; q < 4; ++q) {
            int row = m0 + rb + i * 16 + kg * 4 + q;
            if (row < M) {
                #pragma unroll
                for (int j = 0; j < 4; ++j)
                    C[(size_t)row * BN + cb + j * 16 + ln] = f2bf(acc[i][j][q]);
            }
        }
}

// ---- CSR build -------------------------------------------------------------

__global__ __launch_bounds__(256) void hist_kernel(const int* __restrict__ dst,
                                                   int* __restrict__ deg, int E) {
    int i = blockIdx.x * 256 + threadIdx.x;
    if (i < E) atomicAdd(&deg[dst[i]], 1);
}

__global__ __launch_bounds__(256) void scan_block_kernel(const int* __restrict__ deg,
                                                         int* __restrict__ rowptr,
                                                         int* __restrict__ bsum, int N) {
    __shared__ int s[256];
    int tid = threadIdx.x;
    int i = blockIdx.x * 256 + tid;
    int v = (i < N) ? deg[i] : 0;
    s[tid] = v;
    __syncthreads();
    #pragma unroll
    for (int off = 1; off < 256; off <<= 1) {
        int t = (tid >= off) ? s[tid - off] : 0;
        __syncthreads();
        s[tid] += t;
        __syncthreads();
    }
    if (i < N) rowptr[i] = s[tid] - v;
    if (tid == 255) bsum[blockIdx.x] = s[255];
}

__global__ __launch_bounds__(512) void scan_sums_kernel(int* __restrict__ bsum, int NB) {
    __shared__ int s[512];
    int tid = threadIdx.x;
    int v = (tid < NB) ? bsum[tid] : 0;
    s[tid] = v;
    __syncthreads();
    #pragma unroll
    for (int off = 1; off < 512; off <<= 1) {
        int t = (tid >= off) ? s[tid - off] : 0;
        __syncthreads();
        s[tid] += t;
        __syncthreads();
    }
    if (tid < NB) bsum[tid] = s[tid] - v;
}

__global__ __launch_bounds__(256) void add_off_kernel(int* __restrict__ rowptr,
                                                      const int* __restrict__ bsum,
                                                      int N, int E) {
    int i = blockIdx.x * 256 + threadIdx.x;
    if (i < N) rowptr[i] += bsum[i >> 8];
    if (i == 0) rowptr[N] = E;
}

// Pack (src, weight-bits) as one int2 -> single 8B scattered write per edge.
__global__ __launch_bounds__(256) void fill_kernel(const int* __restrict__ src,
                                                   const int* __restrict__ dst,
                                                   const float* __restrict__ ew,
                                                   const int* __restrict__ rowptr,
                                                   int* __restrict__ cursor,
                                                   int2* __restrict__ csr, int E) {
    int e = blockIdx.x * 256 + threadIdx.x;
    if (e >= E) return;
    int d = dst[e];
    int pos = rowptr[d] + atomicAdd(&cursor[d], 1);
    csr[pos] = make_int2(src[e], __float_as_int(ew[e]));
}

// ---- Aggregation: one wave per dst node, bf16 gather, fused bias+ReLU ------

template <int F, bool OBF>
__global__ __launch_bounds__(256) void agg_kernel(const ushort* __restrict__ sup,
                                                  const int* __restrict__ rowptr,
                                                  const int2* __restrict__ csr,
                                                  const float* __restrict__ bias,
                                                  void* __restrict__ outp, int N) {
    int wid = (blockIdx.x * 256 + threadIdx.x) >> 6;
    int lane = threadIdx.x & 63;
    if (wid >= N) return;
    int start = rowptr[wid], end = rowptr[wid + 1];

    if (F == 128) {
        float ax = 0.f, ay = 0.f;
        for (int c = start; c < end; c += 64) {
            int nn = min(64, end - c);
            int2 sw = make_int2(0, 0);
            if (lane < nn) sw = csr[c + lane];
            for (int j = 0; j < nn; ++j) {
                int sj = __shfl(sw.x, j);
                float wj = __int_as_float(__shfl(sw.y, j));
                uint v = *(const uint*)(sup + (size_t)sj * 128 + lane * 2);
                ax = fmaf(bf_lo(v), wj, ax);
                ay = fmaf(bf_hi(v), wj, ay);
            }
        }
        ax = fmaxf(ax + bias[lane * 2 + 0], 0.f);
        ay = fmaxf(ay + bias[lane * 2 + 1], 0.f);
        if (OBF) {
            ((uint*)outp)[(size_t)wid * 64 + lane] =
                (uint)f2bf(ax) | ((uint)f2bf(ay) << 16);
        } else {
            ((float2*)outp)[(size_t)wid * 64 + lane] = make_float2(ax, ay);
        }
    } else {  // F == 64
        float a0 = 0.f;
        for (int c = start; c < end; c += 64) {
            int nn = min(64, end - c);
            int2 sw = make_int2(0, 0);
            if (lane < nn) sw = csr[c + lane];
            for (int j = 0; j < nn; ++j) {
                int sj = __shfl(sw.x, j);
                float wj = __int_as_float(__shfl(sw.y, j));
                float v = __uint_as_float((uint)sup[(size_t)sj * 64 + lane] << 16);
                a0 = fmaf(v, wj, a0);
            }
        }
        a0 = fmaxf(a0 + bias[lane], 0.f);
        if (OBF) {
            // unused path
        } else {
            ((float*)outp)[(size_t)wid * 64 + lane] = a0;
        }
    }
}

extern "C" void kernel_launch(void* const* d_in, const int* in_sizes, int n_in,
                              void* d_out, int out_size, void* d_ws, size_t ws_size,
                              hipStream_t stream) {
    const float* x  = (const float*)d_in[0];
    const int*   ei = (const int*)d_in[1];
    const float* ew = (const float*)d_in[2];
    const float* W1 = (const float*)d_in[3];
    const float* b1 = (const float*)d_in[4];
    const float* W2 = (const float*)d_in[5];
    const float* b2 = (const float*)d_in[6];
    float* out = (float*)d_out;

    const int N = in_sizes[0] / 128;     // 100000
    const int E = in_sizes[2];           // 1600000
    const int* src = ei;
    const int* dst = ei + E;
    const int NB = (N + 255) / 256;      // <= 512

    // Workspace:
    //   S   [N*128] bf16 : support1, then support2 (N*64 fits)
    //   H1b [N*128] bf16 : relu(agg1+b1), input to gemm2
    //   csr [E] int2, rowptr [N+1], deg+cursor [2N], bsum [512]
    char* ws = (char*)d_ws;
    size_t o = 0;
    ushort* S      = (ushort*)(ws + o); o += (size_t)N * 128 * sizeof(ushort);
    ushort* H1b    = (ushort*)(ws + o); o += (size_t)N * 128 * sizeof(ushort);
    int2*   csr    = (int2*)  (ws + o); o += (size_t)E * sizeof(int2);
    int*    rowptr = (int*)   (ws + o); o += (size_t)(N + 1) * sizeof(int);
    int*    degcur = (int*)   (ws + o); o += (size_t)2 * N * sizeof(int);
    int*    bsum   = (int*)   (ws + o); o += 512 * sizeof(int);
    int* deg    = degcur;
    int* cursor = degcur + N;

    // ---- CSR build ----
    hipMemsetAsync(degcur, 0, (size_t)2 * N * sizeof(int), stream);
    hist_kernel<<<(E + 255) / 256, 256, 0, stream>>>(dst, deg, E);
    scan_block_kernel<<<NB, 256, 0, stream>>>(deg, rowptr, bsum, N);
    scan_sums_kernel<<<1, 512, 0, stream>>>(bsum, NB);
    add_off_kernel<<<NB, 256, 0, stream>>>(rowptr, bsum, N, E);
    fill_kernel<<<(E + 255) / 256, 256, 0, stream>>>(src, dst, ew, rowptr, cursor, csr, E);

    const int GB = (N + 127) / 128;      // 782 gemm blocks

    // ---- layer 1 ----
    gemm_mfma<128, false><<<GB, 256, 0, stream>>>(x, W1, S, N);
    agg_kernel<128, true><<<(N + 3) / 4, 256, 0, stream>>>(S, rowptr, csr, b1, H1b, N);

    // ---- layer 2 ----
    gemm_mfma<64, true><<<GB, 256, 0, stream>>>(H1b, W2, S, N);
    agg_kernel<64, false><<<(N + 3) / 4, 256, 0, stream>>>(S, rowptr, csr, b2, out, N);
}

// Round 4
// 372.089 us; speedup vs baseline: 4.7410x; 1.0862x over previous
//
#include <hip/hip_runtime.h>

// ---------------------------------------------------------------------------
// GCN forward. Hierarchical-binned CSR build + bf16 MFMA GEMMs + gather agg.
//   h1 = relu(segsum(ew * (x@W1)[src] -> dst) + b1)    128 -> 128
//   h2 = relu(segsum(ew * (h1@W2)[src] -> dst) + b2)   128 -> 64
// ---------------------------------------------------------------------------

typedef __attribute__((ext_vector_type(8))) short bf16x8;
typedef __attribute__((ext_vector_type(4))) float f32x4;

__device__ __forceinline__ ushort f2bf(float f) {
    uint u = __float_as_uint(f);
    u += 0x7fff + ((u >> 16) & 1);   // round-to-nearest-even
    return (ushort)(u >> 16);
}
__device__ __forceinline__ float bf_lo(uint bits) { return __uint_as_float(bits << 16); }
__device__ __forceinline__ float bf_hi(uint bits) { return __uint_as_float(bits & 0xffff0000u); }

// ---- W -> bf16, transposed to [n][k] for vector B-fragment loads -----------
__global__ __launch_bounds__(256) void wconv_kernel(const float* __restrict__ W,
                                                    ushort* __restrict__ Wt,
                                                    int K, int Nc) {
    int i = blockIdx.x * 256 + threadIdx.x;
    if (i >= K * Nc) return;
    int k = i / Nc, n = i - k * Nc;
    Wt[(size_t)n * K + k] = f2bf(W[i]);
}

// ---- GEMM: C[M,BN](bf16) = A[M,128] * W[128,BN] ----------------------------
// 256 threads, tile 128 x BN. A in LDS (bf16, XOR swizzle); B frags are 16B
// vector loads from transposed bf16 Wt (L2-hot). fp32 accumulate.
template <int BN, bool ABF16>
__global__ __launch_bounds__(256) void gemm_mfma(const void* __restrict__ Av,
                                                 const ushort* __restrict__ Wt,
                                                 ushort* __restrict__ C, int M) {
    __shared__ ushort As[128 * 128];
    const int tid = threadIdx.x;
    const int m0 = blockIdx.x * 128;

    #pragma unroll
    for (int it = 0; it < 8; ++it) {
        int c = tid + it * 256;
        int r = c >> 4;
        int k8 = (c & 15) << 3;
        int row = m0 + r;
        uint4 w4 = make_uint4(0u, 0u, 0u, 0u);
        if (row < M) {
            if (ABF16) {
                w4 = *(const uint4*)((const ushort*)Av + (size_t)row * 128 + k8);
            } else {
                const float* A = (const float*)Av;
                float4 v0 = *(const float4*)(A + (size_t)row * 128 + k8);
                float4 v1 = *(const float4*)(A + (size_t)row * 128 + k8 + 4);
                w4.x = (uint)f2bf(v0.x) | ((uint)f2bf(v0.y) << 16);
                w4.y = (uint)f2bf(v0.z) | ((uint)f2bf(v0.w) << 16);
                w4.z = (uint)f2bf(v1.x) | ((uint)f2bf(v1.y) << 16);
                w4.w = (uint)f2bf(v1.z) | ((uint)f2bf(v1.w) << 16);
            }
        }
        int byte = (r * 256 + k8 * 2) ^ ((r & 7) << 4);
        *(uint4*)((char*)As + byte) = w4;
    }
    __syncthreads();

    const int wid = tid >> 6, lane = tid & 63;
    constexpr int IF = (BN == 128) ? 4 : 2;
    const int wy = (BN == 128) ? (wid >> 1) : wid;
    const int wx = (BN == 128) ? (wid & 1) : 0;
    const int rb = wy * 16 * IF;
    const int cb = wx * 64;
    const int ln = lane & 15;
    const int kg = lane >> 4;

    f32x4 acc[IF][4];
    #pragma unroll
    for (int i = 0; i < IF; ++i)
        #pragma unroll
        for (int j = 0; j < 4; ++j) acc[i][j] = (f32x4){0.f, 0.f, 0.f, 0.f};

    #pragma unroll
    for (int s = 0; s < 4; ++s) {
        bf16x8 b[4];
        #pragma unroll
        for (int j = 0; j < 4; ++j)
            b[j] = *(const bf16x8*)(Wt + (size_t)(cb + j * 16 + ln) * 128 + s * 32 + kg * 8);
        bf16x8 a[IF];
        #pragma unroll
        for (int i = 0; i < IF; ++i) {
            int r = rb + i * 16 + ln;
            int byte = (r * 256 + s * 64 + kg * 16) ^ ((r & 7) << 4);
            a[i] = *(const bf16x8*)((const char*)As + byte);
        }
        #pragma unroll
        for (int i = 0; i < IF; ++i)
            #pragma unroll
            for (int j = 0; j < 4; ++j)
                acc[i][j] = __builtin_amdgcn_mfma_f32_16x16x32_bf16(a[i], b[j], acc[i][j], 0, 0, 0);
    }

    #pragma unroll
    for (int i = 0; i < IF; ++i)
        #pragma unroll
        for (int q = 0; q < 4; ++q) {
            int row = m0 + rb + i * 16 + kg * 4 + q;
            if (row < M) {
                #pragma unroll
                for (int j = 0; j < 4; ++j)
                    C[(size_t)row * BN + cb + j * 16 + ln] = f2bf(acc[i][j][q]);
            }
        }
}

// ---- CSR build -------------------------------------------------------------

__global__ __launch_bounds__(256) void hist_kernel(const int* __restrict__ dst,
                                                   int* __restrict__ deg, int E) {
    int i = blockIdx.x * 256 + threadIdx.x;
    if (i < E) atomicAdd(&deg[dst[i]], 1);
}

__global__ __launch_bounds__(256) void scan_block_kernel(const int* __restrict__ deg,
                                                         int* __restrict__ rowptr,
                                                         int* __restrict__ bsum, int N) {
    __shared__ int s[256];
    int tid = threadIdx.x;
    int i = blockIdx.x * 256 + tid;
    int v = (i < N) ? deg[i] : 0;
    s[tid] = v;
    __syncthreads();
    #pragma unroll
    for (int off = 1; off < 256; off <<= 1) {
        int t = (tid >= off) ? s[tid - off] : 0;
        __syncthreads();
        s[tid] += t;
        __syncthreads();
    }
    if (i < N) rowptr[i] = s[tid] - v;
    if (tid == 255) bsum[blockIdx.x] = s[255];
}

__global__ __launch_bounds__(512) void scan_sums_kernel(int* __restrict__ bsum, int NB) {
    __shared__ int s[512];
    int tid = threadIdx.x;
    int v = (tid < NB) ? bsum[tid] : 0;
    s[tid] = v;
    __syncthreads();
    #pragma unroll
    for (int off = 1; off < 512; off <<= 1) {
        int t = (tid >= off) ? s[tid - off] : 0;
        __syncthreads();
        s[tid] += t;
        __syncthreads();
    }
    if (tid < NB) bsum[tid] = s[tid] - v;
}

__global__ __launch_bounds__(256) void add_off_kernel(int* __restrict__ rowptr,
                                                      const int* __restrict__ bsum,
                                                      int N, int E) {
    int i = blockIdx.x * 256 + threadIdx.x;
    if (i < N) rowptr[i] += bsum[i >> 8];
    if (i == 0) rowptr[N] = E;
}

// ccur[c] = rowptr[c*512] (coarse-bucket write cursors for binA)
__global__ __launch_bounds__(256) void curinit_kernel(const int* __restrict__ rowptr,
                                                      int* __restrict__ ccur, int NCB) {
    int i = threadIdx.x;
    if (i < NCB) ccur[i] = rowptr[i << 9];
}

// binA: LDS counting-sort 4096-edge chunks into coarse buckets (dst>>9),
// grouped coalesced writes into globally reserved ranges.
#define NCB_PAD 256
__global__ __launch_bounds__(256) void binA_kernel(const int* __restrict__ src,
                                                   const int* __restrict__ dst,
                                                   const float* __restrict__ ew,
                                                   int* __restrict__ ccur,
                                                   uint2* __restrict__ ebuf, int E) {
    __shared__ int lh[NCB_PAD];
    __shared__ int loff[NCB_PAD];
    __shared__ int gpos[NCB_PAD];
    __shared__ uint2 stage[4096];
    __shared__ unsigned char sbuck[4096];
    const int tid = threadIdx.x;
    const int base = blockIdx.x * 4096;
    const int nn = min(4096, E - base);

    lh[tid] = 0;
    __syncthreads();

    uint pk[16], wb[16];
    short bk[16];
    short rk[16];
    #pragma unroll
    for (int i = 0; i < 16; ++i) {
        int li = tid + i * 256;
        bk[i] = -1;
        if (li < nn) {
            int e = base + li;
            int d = dst[e];
            int b = d >> 9;
            pk[i] = (uint)src[e] | ((uint)(d & 511) << 17);
            wb[i] = __float_as_uint(ew[e]);
            bk[i] = (short)b;
            rk[i] = (short)atomicAdd(&lh[b], 1);
        }
    }
    __syncthreads();

    // exclusive scan of lh into loff
    int v = lh[tid];
    loff[tid] = v;
    __syncthreads();
    #pragma unroll
    for (int off = 1; off < 256; off <<= 1) {
        int t = (tid >= off) ? loff[tid - off] : 0;
        __syncthreads();
        loff[tid] += t;
        __syncthreads();
    }
    int excl = loff[tid] - v;
    __syncthreads();
    loff[tid] = excl;
    gpos[tid] = (v > 0) ? atomicAdd(&ccur[tid], v) : 0;
    __syncthreads();

    #pragma unroll
    for (int i = 0; i < 16; ++i)
        if (bk[i] >= 0) {
            int s = loff[bk[i]] + rk[i];
            stage[s] = make_uint2(pk[i], wb[i]);
            sbuck[s] = (unsigned char)bk[i];
        }
    __syncthreads();

    for (int s = tid; s < nn; s += 256) {
        uint2 e2 = stage[s];
        int b = sbuck[s];
        ebuf[gpos[b] + (s - loff[b])] = e2;
    }
}

// binB: one block per coarse bucket; exact CSR position via per-node LDS
// cursors. Writes land in the bucket's own contiguous CSR window (L2-local).
__global__ __launch_bounds__(512) void binB_kernel(const uint2* __restrict__ ebuf,
                                                   const int* __restrict__ rowptr,
                                                   int2* __restrict__ csr, int N) {
    __shared__ int cur[512];
    const int c = blockIdx.x;
    const int tid = threadIdx.x;
    const int n0 = c << 9;
    cur[tid] = (n0 + tid < N) ? rowptr[n0 + tid] : 0;
    __syncthreads();
    const int cbase = rowptr[n0];
    const int cend = rowptr[min(n0 + 512, N)];
    for (int e = cbase + tid; e < cend; e += 512) {
        uint2 v = ebuf[e];
        int fine = v.x >> 17;
        int pos = atomicAdd(&cur[fine], 1);
        csr[pos] = make_int2((int)(v.x & 0x1FFFF), (int)v.y);
    }
}

// ---- Aggregation: one wave per dst node, bf16 gather, fused bias+ReLU ------

template <int F, bool OBF>
__global__ __launch_bounds__(256) void agg_kernel(const ushort* __restrict__ sup,
                                                  const int* __restrict__ rowptr,
                                                  const int2* __restrict__ csr,
                                                  const float* __restrict__ bias,
                                                  void* __restrict__ outp, int N) {
    int wid = (blockIdx.x * 256 + threadIdx.x) >> 6;
    int lane = threadIdx.x & 63;
    if (wid >= N) return;
    int start = rowptr[wid], end = rowptr[wid + 1];

    if (F == 128) {
        float ax = 0.f, ay = 0.f;
        for (int c = start; c < end; c += 64) {
            int nn = min(64, end - c);
            int2 sw = make_int2(0, 0);
            if (lane < nn) sw = csr[c + lane];
            for (int j = 0; j < nn; ++j) {
                int sj = __shfl(sw.x, j);
                float wj = __int_as_float(__shfl(sw.y, j));
                uint v = *(const uint*)(sup + (size_t)sj * 128 + lane * 2);
                ax = fmaf(bf_lo(v), wj, ax);
                ay = fmaf(bf_hi(v), wj, ay);
            }
        }
        ax = fmaxf(ax + bias[lane * 2 + 0], 0.f);
        ay = fmaxf(ay + bias[lane * 2 + 1], 0.f);
        if (OBF) {
            ((uint*)outp)[(size_t)wid * 64 + lane] =
                (uint)f2bf(ax) | ((uint)f2bf(ay) << 16);
        } else {
            ((float2*)outp)[(size_t)wid * 64 + lane] = make_float2(ax, ay);
        }
    } else {  // F == 64
        float a0 = 0.f;
        for (int c = start; c < end; c += 64) {
            int nn = min(64, end - c);
            int2 sw = make_int2(0, 0);
            if (lane < nn) sw = csr[c + lane];
            for (int j = 0; j < nn; ++j) {
                int sj = __shfl(sw.x, j);
                float wj = __int_as_float(__shfl(sw.y, j));
                float v = __uint_as_float((uint)sup[(size_t)sj * 64 + lane] << 16);
                a0 = fmaf(v, wj, a0);
            }
        }
        ((float*)outp)[(size_t)wid * 64 + lane] = fmaxf(a0 + bias[lane], 0.f);
    }
}

extern "C" void kernel_launch(void* const* d_in, const int* in_sizes, int n_in,
                              void* d_out, int out_size, void* d_ws, size_t ws_size,
                              hipStream_t stream) {
    const float* x  = (const float*)d_in[0];
    const int*   ei = (const int*)d_in[1];
    const float* ew = (const float*)d_in[2];
    const float* W1 = (const float*)d_in[3];
    const float* b1 = (const float*)d_in[4];
    const float* W2 = (const float*)d_in[5];
    const float* b2 = (const float*)d_in[6];
    float* out = (float*)d_out;

    const int N = in_sizes[0] / 128;     // 100000
    const int E = in_sizes[2];           // 1600000
    const int* src = ei;
    const int* dst = ei + E;
    const int NB = (N + 255) / 256;      // rowptr scan blocks (<= 512)
    const int NCB = (N + 511) / 512;     // coarse buckets (196)

    char* ws = (char*)d_ws;
    size_t o = 0;
    ushort* S      = (ushort*)(ws + o); o += (size_t)N * 128 * sizeof(ushort);
    ushort* H1b    = (ushort*)(ws + o); o += (size_t)N * 128 * sizeof(ushort);
    uint2*  ebuf   = (uint2*) (ws + o); o += (size_t)E * sizeof(uint2);
    int2*   csr    = (int2*)  (ws + o); o += (size_t)E * sizeof(int2);
    int*    rowptr = (int*)   (ws + o); o += (size_t)(N + 1) * sizeof(int);
    int*    deg    = (int*)   (ws + o); o += (size_t)N * sizeof(int);
    int*    ccur   = (int*)   (ws + o); o += NCB_PAD * sizeof(int);
    int*    bsum   = (int*)   (ws + o); o += 512 * sizeof(int);
    ushort* Wt1    = (ushort*)(ws + o); o += 128 * 128 * sizeof(ushort);
    ushort* Wt2    = (ushort*)(ws + o); o += 128 * 64 * sizeof(ushort);

    // ---- weights -> transposed bf16 ----
    wconv_kernel<<<(128 * 128 + 255) / 256, 256, 0, stream>>>(W1, Wt1, 128, 128);
    wconv_kernel<<<(128 * 64 + 255) / 256, 256, 0, stream>>>(W2, Wt2, 128, 64);

    // ---- CSR build ----
    hipMemsetAsync(deg, 0, (size_t)N * sizeof(int), stream);
    hist_kernel<<<(E + 255) / 256, 256, 0, stream>>>(dst, deg, E);
    scan_block_kernel<<<NB, 256, 0, stream>>>(deg, rowptr, bsum, N);
    scan_sums_kernel<<<1, 512, 0, stream>>>(bsum, NB);
    add_off_kernel<<<NB, 256, 0, stream>>>(rowptr, bsum, N, E);
    curinit_kernel<<<1, 256, 0, stream>>>(rowptr, ccur, NCB);
    binA_kernel<<<(E + 4095) / 4096, 256, 0, stream>>>(src, dst, ew, ccur, ebuf, E);
    binB_kernel<<<NCB, 512, 0, stream>>>(ebuf, rowptr, csr, N);

    const int GB = (N + 127) / 128;

    // ---- layer 1 ----
    gemm_mfma<128, false><<<GB, 256, 0, stream>>>(x, Wt1, S, N);
    agg_kernel<128, true><<<(N + 3) / 4, 256, 0, stream>>>(S, rowptr, csr, b1, H1b, N);

    // ---- layer 2 ----
    gemm_mfma<64, true><<<GB, 256, 0, stream>>>(H1b, Wt2, S, N);
    agg_kernel<64, false><<<(N + 3) / 4, 256, 0, stream>>>(S, rowptr, csr, b2, out, N);
}

// Round 5
// 313.446 us; speedup vs baseline: 5.6280x; 1.1871x over previous
//
#include <hip/hip_runtime.h>

// ---------------------------------------------------------------------------
// GCN forward. Hierarchical-binned CSR build + bf16 MFMA GEMMs + gather agg.
//   h1 = relu(segsum(ew * (x@W1)[src] -> dst) + b1)    128 -> 128
//   h2 = relu(segsum(ew * (h1@W2)[src] -> dst) + b2)   128 -> 64
// agg inner loop: wave-uniform scalar csr reads + 8x unrolled gathers (MLP).
// ---------------------------------------------------------------------------

typedef __attribute__((ext_vector_type(8))) short bf16x8;
typedef __attribute__((ext_vector_type(4))) float f32x4;

__device__ __forceinline__ ushort f2bf(float f) {
    uint u = __float_as_uint(f);
    u += 0x7fff + ((u >> 16) & 1);   // round-to-nearest-even
    return (ushort)(u >> 16);
}
__device__ __forceinline__ float bf_lo(uint bits) { return __uint_as_float(bits << 16); }
__device__ __forceinline__ float bf_hi(uint bits) { return __uint_as_float(bits & 0xffff0000u); }

// ---- W -> bf16, transposed to [n][k] for vector B-fragment loads -----------
__global__ __launch_bounds__(256) void wconv_kernel(const float* __restrict__ W,
                                                    ushort* __restrict__ Wt,
                                                    int K, int Nc) {
    int i = blockIdx.x * 256 + threadIdx.x;
    if (i >= K * Nc) return;
    int k = i / Nc, n = i - k * Nc;
    Wt[(size_t)n * K + k] = f2bf(W[i]);
}

// ---- GEMM: C[M,BN](bf16) = A[M,128] * W[128,BN] ----------------------------
template <int BN, bool ABF16>
__global__ __launch_bounds__(256) void gemm_mfma(const void* __restrict__ Av,
                                                 const ushort* __restrict__ Wt,
                                                 ushort* __restrict__ C, int M) {
    __shared__ ushort As[128 * 128];
    const int tid = threadIdx.x;
    const int m0 = blockIdx.x * 128;

    #pragma unroll
    for (int it = 0; it < 8; ++it) {
        int c = tid + it * 256;
        int r = c >> 4;
        int k8 = (c & 15) << 3;
        int row = m0 + r;
        uint4 w4 = make_uint4(0u, 0u, 0u, 0u);
        if (row < M) {
            if (ABF16) {
                w4 = *(const uint4*)((const ushort*)Av + (size_t)row * 128 + k8);
            } else {
                const float* A = (const float*)Av;
                float4 v0 = *(const float4*)(A + (size_t)row * 128 + k8);
                float4 v1 = *(const float4*)(A + (size_t)row * 128 + k8 + 4);
                w4.x = (uint)f2bf(v0.x) | ((uint)f2bf(v0.y) << 16);
                w4.y = (uint)f2bf(v0.z) | ((uint)f2bf(v0.w) << 16);
                w4.z = (uint)f2bf(v1.x) | ((uint)f2bf(v1.y) << 16);
                w4.w = (uint)f2bf(v1.z) | ((uint)f2bf(v1.w) << 16);
            }
        }
        int byte = (r * 256 + k8 * 2) ^ ((r & 7) << 4);
        *(uint4*)((char*)As + byte) = w4;
    }
    __syncthreads();

    const int wid = tid >> 6, lane = tid & 63;
    constexpr int IF = (BN == 128) ? 4 : 2;
    const int wy = (BN == 128) ? (wid >> 1) : wid;
    const int wx = (BN == 128) ? (wid & 1) : 0;
    const int rb = wy * 16 * IF;
    const int cb = wx * 64;
    const int ln = lane & 15;
    const int kg = lane >> 4;

    f32x4 acc[IF][4];
    #pragma unroll
    for (int i = 0; i < IF; ++i)
        #pragma unroll
        for (int j = 0; j < 4; ++j) acc[i][j] = (f32x4){0.f, 0.f, 0.f, 0.f};

    #pragma unroll
    for (int s = 0; s < 4; ++s) {
        bf16x8 b[4];
        #pragma unroll
        for (int j = 0; j < 4; ++j)
            b[j] = *(const bf16x8*)(Wt + (size_t)(cb + j * 16 + ln) * 128 + s * 32 + kg * 8);
        bf16x8 a[IF];
        #pragma unroll
        for (int i = 0; i < IF; ++i) {
            int r = rb + i * 16 + ln;
            int byte = (r * 256 + s * 64 + kg * 16) ^ ((r & 7) << 4);
            a[i] = *(const bf16x8*)((const char*)As + byte);
        }
        #pragma unroll
        for (int i = 0; i < IF; ++i)
            #pragma unroll
            for (int j = 0; j < 4; ++j)
                acc[i][j] = __builtin_amdgcn_mfma_f32_16x16x32_bf16(a[i], b[j], acc[i][j], 0, 0, 0);
    }

    #pragma unroll
    for (int i = 0; i < IF; ++i)
        #pragma unroll
        for (int q = 0; q < 4; ++q) {
            int row = m0 + rb + i * 16 + kg * 4 + q;
            if (row < M) {
                #pragma unroll
                for (int j = 0; j < 4; ++j)
                    C[(size_t)row * BN + cb + j * 16 + ln] = f2bf(acc[i][j][q]);
            }
        }
}

// ---- CSR build -------------------------------------------------------------

__global__ __launch_bounds__(256) void hist_kernel(const int* __restrict__ dst,
                                                   int* __restrict__ deg, int E) {
    int i = blockIdx.x * 256 + threadIdx.x;
    if (i < E) atomicAdd(&deg[dst[i]], 1);
}

__global__ __launch_bounds__(256) void scan_block_kernel(const int* __restrict__ deg,
                                                         int* __restrict__ rowptr,
                                                         int* __restrict__ bsum, int N) {
    __shared__ int s[256];
    int tid = threadIdx.x;
    int i = blockIdx.x * 256 + tid;
    int v = (i < N) ? deg[i] : 0;
    s[tid] = v;
    __syncthreads();
    #pragma unroll
    for (int off = 1; off < 256; off <<= 1) {
        int t = (tid >= off) ? s[tid - off] : 0;
        __syncthreads();
        s[tid] += t;
        __syncthreads();
    }
    if (i < N) rowptr[i] = s[tid] - v;
    if (tid == 255) bsum[blockIdx.x] = s[255];
}

__global__ __launch_bounds__(512) void scan_sums_kernel(int* __restrict__ bsum, int NB) {
    __shared__ int s[512];
    int tid = threadIdx.x;
    int v = (tid < NB) ? bsum[tid] : 0;
    s[tid] = v;
    __syncthreads();
    #pragma unroll
    for (int off = 1; off < 512; off <<= 1) {
        int t = (tid >= off) ? s[tid - off] : 0;
        __syncthreads();
        s[tid] += t;
        __syncthreads();
    }
    if (tid < NB) bsum[tid] = s[tid] - v;
}

__global__ __launch_bounds__(256) void add_off_kernel(int* __restrict__ rowptr,
                                                      const int* __restrict__ bsum,
                                                      int N, int E) {
    int i = blockIdx.x * 256 + threadIdx.x;
    if (i < N) rowptr[i] += bsum[i >> 8];
    if (i == 0) rowptr[N] = E;
}

__global__ __launch_bounds__(256) void curinit_kernel(const int* __restrict__ rowptr,
                                                      int* __restrict__ ccur, int NCB) {
    int i = threadIdx.x;
    if (i < NCB) ccur[i] = rowptr[i << 9];
}

// binA: LDS counting-sort 4096-edge chunks into coarse buckets (dst>>9),
// grouped coalesced writes into globally reserved ranges.
#define NCB_PAD 256
__global__ __launch_bounds__(256) void binA_kernel(const int* __restrict__ src,
                                                   const int* __restrict__ dst,
                                                   const float* __restrict__ ew,
                                                   int* __restrict__ ccur,
                                                   uint2* __restrict__ ebuf, int E) {
    __shared__ int lh[NCB_PAD];
    __shared__ int loff[NCB_PAD];
    __shared__ int gpos[NCB_PAD];
    __shared__ uint2 stage[4096];
    __shared__ unsigned char sbuck[4096];
    const int tid = threadIdx.x;
    const int base = blockIdx.x * 4096;
    const int nn = min(4096, E - base);

    lh[tid] = 0;
    __syncthreads();

    uint pk[16], wb[16];
    short bk[16];
    short rk[16];
    #pragma unroll
    for (int i = 0; i < 16; ++i) {
        int li = tid + i * 256;
        bk[i] = -1;
        if (li < nn) {
            int e = base + li;
            int d = dst[e];
            int b = d >> 9;
            pk[i] = (uint)src[e] | ((uint)(d & 511) << 17);
            wb[i] = __float_as_uint(ew[e]);
            bk[i] = (short)b;
            rk[i] = (short)atomicAdd(&lh[b], 1);
        }
    }
    __syncthreads();

    int v = lh[tid];
    loff[tid] = v;
    __syncthreads();
    #pragma unroll
    for (int off = 1; off < 256; off <<= 1) {
        int t = (tid >= off) ? loff[tid - off] : 0;
        __syncthreads();
        loff[tid] += t;
        __syncthreads();
    }
    int excl = loff[tid] - v;
    __syncthreads();
    loff[tid] = excl;
    gpos[tid] = (v > 0) ? atomicAdd(&ccur[tid], v) : 0;
    __syncthreads();

    #pragma unroll
    for (int i = 0; i < 16; ++i)
        if (bk[i] >= 0) {
            int s = loff[bk[i]] + rk[i];
            stage[s] = make_uint2(pk[i], wb[i]);
            sbuck[s] = (unsigned char)bk[i];
        }
    __syncthreads();

    for (int s = tid; s < nn; s += 256) {
        uint2 e2 = stage[s];
        int b = sbuck[s];
        ebuf[gpos[b] + (s - loff[b])] = e2;
    }
}

// binB: one block per coarse bucket; exact CSR position via per-node LDS
// cursors. Writes land in the bucket's own contiguous CSR window (L2-local).
__global__ __launch_bounds__(512) void binB_kernel(const uint2* __restrict__ ebuf,
                                                   const int* __restrict__ rowptr,
                                                   int2* __restrict__ csr, int N) {
    __shared__ int cur[512];
    const int c = blockIdx.x;
    const int tid = threadIdx.x;
    const int n0 = c << 9;
    cur[tid] = (n0 + tid < N) ? rowptr[n0 + tid] : 0;
    __syncthreads();
    const int cbase = rowptr[n0];
    const int cend = rowptr[min(n0 + 512, N)];
    for (int e = cbase + tid; e < cend; e += 512) {
        uint2 v = ebuf[e];
        int fine = v.x >> 17;
        int pos = atomicAdd(&cur[fine], 1);
        csr[pos] = make_int2((int)(v.x & 0x1FFFF), (int)v.y);
    }
}

// ---- Aggregation: one wave per dst node ------------------------------------
// csr[j] reads are wave-uniform -> scalar loads; gathers unrolled x8 for MLP.

template <int F, bool OBF>
__global__ __launch_bounds__(256) void agg_kernel(const ushort* __restrict__ sup,
                                                  const int* __restrict__ rowptr,
                                                  const int2* __restrict__ csr,
                                                  const float* __restrict__ bias,
                                                  void* __restrict__ outp, int N) {
    int wid = (blockIdx.x * 256 + threadIdx.x) >> 6;
    int lane = threadIdx.x & 63;
    if (wid >= N) return;
    const int start = rowptr[wid], end = rowptr[wid + 1];

    if (F == 128) {
        float ax = 0.f, ay = 0.f;
        const ushort* rp = sup + lane * 2;
        int j = start;
        for (; j + 8 <= end; j += 8) {
            int2 e0 = csr[j + 0], e1 = csr[j + 1], e2 = csr[j + 2], e3 = csr[j + 3];
            int2 e4 = csr[j + 4], e5 = csr[j + 5], e6 = csr[j + 6], e7 = csr[j + 7];
            uint v0 = *(const uint*)(rp + (size_t)e0.x * 128);
            uint v1 = *(const uint*)(rp + (size_t)e1.x * 128);
            uint v2 = *(const uint*)(rp + (size_t)e2.x * 128);
            uint v3 = *(const uint*)(rp + (size_t)e3.x * 128);
            uint v4 = *(const uint*)(rp + (size_t)e4.x * 128);
            uint v5 = *(const uint*)(rp + (size_t)e5.x * 128);
            uint v6 = *(const uint*)(rp + (size_t)e6.x * 128);
            uint v7 = *(const uint*)(rp + (size_t)e7.x * 128);
            float w0 = __int_as_float(e0.y), w1 = __int_as_float(e1.y);
            float w2 = __int_as_float(e2.y), w3 = __int_as_float(e3.y);
            float w4 = __int_as_float(e4.y), w5 = __int_as_float(e5.y);
            float w6 = __int_as_float(e6.y), w7 = __int_as_float(e7.y);
            ax = fmaf(bf_lo(v0), w0, ax); ay = fmaf(bf_hi(v0), w0, ay);
            ax = fmaf(bf_lo(v1), w1, ax); ay = fmaf(bf_hi(v1), w1, ay);
            ax = fmaf(bf_lo(v2), w2, ax); ay = fmaf(bf_hi(v2), w2, ay);
            ax = fmaf(bf_lo(v3), w3, ax); ay = fmaf(bf_hi(v3), w3, ay);
            ax = fmaf(bf_lo(v4), w4, ax); ay = fmaf(bf_hi(v4), w4, ay);
            ax = fmaf(bf_lo(v5), w5, ax); ay = fmaf(bf_hi(v5), w5, ay);
            ax = fmaf(bf_lo(v6), w6, ax); ay = fmaf(bf_hi(v6), w6, ay);
            ax = fmaf(bf_lo(v7), w7, ax); ay = fmaf(bf_hi(v7), w7, ay);
        }
        for (; j < end; ++j) {
            int2 e = csr[j];
            float w = __int_as_float(e.y);
            uint v = *(const uint*)(rp + (size_t)e.x * 128);
            ax = fmaf(bf_lo(v), w, ax);
            ay = fmaf(bf_hi(v), w, ay);
        }
        ax = fmaxf(ax + bias[lane * 2 + 0], 0.f);
        ay = fmaxf(ay + bias[lane * 2 + 1], 0.f);
        if (OBF) {
            ((uint*)outp)[(size_t)wid * 64 + lane] =
                (uint)f2bf(ax) | ((uint)f2bf(ay) << 16);
        } else {
            ((float2*)outp)[(size_t)wid * 64 + lane] = make_float2(ax, ay);
        }
    } else {  // F == 64
        float a0 = 0.f;
        const ushort* rp = sup + lane;
        int j = start;
        for (; j + 8 <= end; j += 8) {
            int2 e0 = csr[j + 0], e1 = csr[j + 1], e2 = csr[j + 2], e3 = csr[j + 3];
            int2 e4 = csr[j + 4], e5 = csr[j + 5], e6 = csr[j + 6], e7 = csr[j + 7];
            ushort v0 = rp[(size_t)e0.x * 64];
            ushort v1 = rp[(size_t)e1.x * 64];
            ushort v2 = rp[(size_t)e2.x * 64];
            ushort v3 = rp[(size_t)e3.x * 64];
            ushort v4 = rp[(size_t)e4.x * 64];
            ushort v5 = rp[(size_t)e5.x * 64];
            ushort v6 = rp[(size_t)e6.x * 64];
            ushort v7 = rp[(size_t)e7.x * 64];
            a0 = fmaf(__uint_as_float((uint)v0 << 16), __int_as_float(e0.y), a0);
            a0 = fmaf(__uint_as_float((uint)v1 << 16), __int_as_float(e1.y), a0);
            a0 = fmaf(__uint_as_float((uint)v2 << 16), __int_as_float(e2.y), a0);
            a0 = fmaf(__uint_as_float((uint)v3 << 16), __int_as_float(e3.y), a0);
            a0 = fmaf(__uint_as_float((uint)v4 << 16), __int_as_float(e4.y), a0);
            a0 = fmaf(__uint_as_float((uint)v5 << 16), __int_as_float(e5.y), a0);
            a0 = fmaf(__uint_as_float((uint)v6 << 16), __int_as_float(e6.y), a0);
            a0 = fmaf(__uint_as_float((uint)v7 << 16), __int_as_float(e7.y), a0);
        }
        for (; j < end; ++j) {
            int2 e = csr[j];
            ushort v = rp[(size_t)e.x * 64];
            a0 = fmaf(__uint_as_float((uint)v << 16), __int_as_float(e.y), a0);
        }
        ((float*)outp)[(size_t)wid * 64 + lane] = fmaxf(a0 + bias[lane], 0.f);
    }
}

extern "C" void kernel_launch(void* const* d_in, const int* in_sizes, int n_in,
                              void* d_out, int out_size, void* d_ws, size_t ws_size,
                              hipStream_t stream) {
    const float* x  = (const float*)d_in[0];
    const int*   ei = (const int*)d_in[1];
    const float* ew = (const float*)d_in[2];
    const float* W1 = (const float*)d_in[3];
    const float* b1 = (const float*)d_in[4];
    const float* W2 = (const float*)d_in[5];
    const float* b2 = (const float*)d_in[6];
    float* out = (float*)d_out;

    const int N = in_sizes[0] / 128;     // 100000
    const int E = in_sizes[2];           // 1600000
    const int* src = ei;
    const int* dst = ei + E;
    const int NB = (N + 255) / 256;
    const int NCB = (N + 511) / 512;

    char* ws = (char*)d_ws;
    size_t o = 0;
    ushort* S      = (ushort*)(ws + o); o += (size_t)N * 128 * sizeof(ushort);
    ushort* H1b    = (ushort*)(ws + o); o += (size_t)N * 128 * sizeof(ushort);
    uint2*  ebuf   = (uint2*) (ws + o); o += (size_t)E * sizeof(uint2);
    int2*   csr    = (int2*)  (ws + o); o += (size_t)E * sizeof(int2);
    int*    rowptr = (int*)   (ws + o); o += (size_t)(N + 1) * sizeof(int);
    int*    deg    = (int*)   (ws + o); o += (size_t)N * sizeof(int);
    int*    ccur   = (int*)   (ws + o); o += NCB_PAD * sizeof(int);
    int*    bsum   = (int*)   (ws + o); o += 512 * sizeof(int);
    ushort* Wt1    = (ushort*)(ws + o); o += 128 * 128 * sizeof(ushort);
    ushort* Wt2    = (ushort*)(ws + o); o += 128 * 64 * sizeof(ushort);

    wconv_kernel<<<(128 * 128 + 255) / 256, 256, 0, stream>>>(W1, Wt1, 128, 128);
    wconv_kernel<<<(128 * 64 + 255) / 256, 256, 0, stream>>>(W2, Wt2, 128, 64);

    hipMemsetAsync(deg, 0, (size_t)N * sizeof(int), stream);
    hist_kernel<<<(E + 255) / 256, 256, 0, stream>>>(dst, deg, E);
    scan_block_kernel<<<NB, 256, 0, stream>>>(deg, rowptr, bsum, N);
    scan_sums_kernel<<<1, 512, 0, stream>>>(bsum, NB);
    add_off_kernel<<<NB, 256, 0, stream>>>(rowptr, bsum, N, E);
    curinit_kernel<<<1, 256, 0, stream>>>(rowptr, ccur, NCB);
    binA_kernel<<<(E + 4095) / 4096, 256, 0, stream>>>(src, dst, ew, ccur, ebuf, E);
    binB_kernel<<<NCB, 512, 0, stream>>>(ebuf, rowptr, csr, N);

    const int GB = (N + 127) / 128;

    gemm_mfma<128, false><<<GB, 256, 0, stream>>>(x, Wt1, S, N);
    agg_kernel<128, true><<<(N + 3) / 4, 256, 0, stream>>>(S, rowptr, csr, b1, H1b, N);

    gemm_mfma<64, true><<<GB, 256, 0, stream>>>(H1b, Wt2, S, N);
    agg_kernel<64, false><<<(N + 3) / 4, 256, 0, stream>>>(S, rowptr, csr, b2, out, N);
}

// Round 6
// 240.878 us; speedup vs baseline: 7.3235x; 1.3013x over previous
//
#include <hip/hip_runtime.h>

// ---------------------------------------------------------------------------
// GCN forward. Coarse-binned CSR build (no per-node global hist) +
// bf16 MFMA GEMMs + 16-deep-MLP gather aggregation.
//   h1 = relu(segsum(ew * (x@W1)[src] -> dst) + b1)    128 -> 128
//   h2 = relu(segsum(ew * (h1@W2)[src] -> dst) + b2)   128 -> 64
// ---------------------------------------------------------------------------

typedef __attribute__((ext_vector_type(8))) short bf16x8;
typedef __attribute__((ext_vector_type(4))) float f32x4;

__device__ __forceinline__ ushort f2bf(float f) {
    uint u = __float_as_uint(f);
    u += 0x7fff + ((u >> 16) & 1);   // round-to-nearest-even
    return (ushort)(u >> 16);
}
__device__ __forceinline__ float bf_lo(uint bits) { return __uint_as_float(bits << 16); }
__device__ __forceinline__ float bf_hi(uint bits) { return __uint_as_float(bits & 0xffff0000u); }

// ---- W1,W2 -> bf16 transposed [n][k] (single launch) -----------------------
__global__ __launch_bounds__(256) void wconv_kernel(const float* __restrict__ W1,
                                                    ushort* __restrict__ Wt1,
                                                    const float* __restrict__ W2,
                                                    ushort* __restrict__ Wt2) {
    int i = blockIdx.x * 256 + threadIdx.x;
    if (i < 128 * 128) {
        int k = i >> 7, n = i & 127;
        Wt1[n * 128 + k] = f2bf(W1[i]);
    } else {
        int i2 = i - 128 * 128;
        if (i2 < 128 * 64) {
            int k = i2 >> 6, n = i2 & 63;
            Wt2[n * 128 + k] = f2bf(W2[i2]);
        }
    }
}

// ---- GEMM: C[M,BN](bf16) = A[M,128] * W[128,BN] ----------------------------
template <int BN, bool ABF16>
__global__ __launch_bounds__(256) void gemm_mfma(const void* __restrict__ Av,
                                                 const ushort* __restrict__ Wt,
                                                 ushort* __restrict__ C, int M) {
    __shared__ ushort As[128 * 128];
    const int tid = threadIdx.x;
    const int m0 = blockIdx.x * 128;

    #pragma unroll
    for (int it = 0; it < 8; ++it) {
        int c = tid + it * 256;
        int r = c >> 4;
        int k8 = (c & 15) << 3;
        int row = m0 + r;
        uint4 w4 = make_uint4(0u, 0u, 0u, 0u);
        if (row < M) {
            if (ABF16) {
                w4 = *(const uint4*)((const ushort*)Av + (size_t)row * 128 + k8);
            } else {
                const float* A = (const float*)Av;
                float4 v0 = *(const float4*)(A + (size_t)row * 128 + k8);
                float4 v1 = *(const float4*)(A + (size_t)row * 128 + k8 + 4);
                w4.x = (uint)f2bf(v0.x) | ((uint)f2bf(v0.y) << 16);
                w4.y = (uint)f2bf(v0.z) | ((uint)f2bf(v0.w) << 16);
                w4.z = (uint)f2bf(v1.x) | ((uint)f2bf(v1.y) << 16);
                w4.w = (uint)f2bf(v1.z) | ((uint)f2bf(v1.w) << 16);
            }
        }
        int byte = (r * 256 + k8 * 2) ^ ((r & 7) << 4);
        *(uint4*)((char*)As + byte) = w4;
    }
    __syncthreads();

    const int wid = tid >> 6, lane = tid & 63;
    constexpr int IF = (BN == 128) ? 4 : 2;
    const int wy = (BN == 128) ? (wid >> 1) : wid;
    const int wx = (BN == 128) ? (wid & 1) : 0;
    const int rb = wy * 16 * IF;
    const int cb = wx * 64;
    const int ln = lane & 15;
    const int kg = lane >> 4;

    f32x4 acc[IF][4];
    #pragma unroll
    for (int i = 0; i < IF; ++i)
        #pragma unroll
        for (int j = 0; j < 4; ++j) acc[i][j] = (f32x4){0.f, 0.f, 0.f, 0.f};

    #pragma unroll
    for (int s = 0; s < 4; ++s) {
        bf16x8 b[4];
        #pragma unroll
        for (int j = 0; j < 4; ++j)
            b[j] = *(const bf16x8*)(Wt + (size_t)(cb + j * 16 + ln) * 128 + s * 32 + kg * 8);
        bf16x8 a[IF];
        #pragma unroll
        for (int i = 0; i < IF; ++i) {
            int r = rb + i * 16 + ln;
            int byte = (r * 256 + s * 64 + kg * 16) ^ ((r & 7) << 4);
            a[i] = *(const bf16x8*)((const char*)As + byte);
        }
        #pragma unroll
        for (int i = 0; i < IF; ++i)
            #pragma unroll
            for (int j = 0; j < 4; ++j)
                acc[i][j] = __builtin_amdgcn_mfma_f32_16x16x32_bf16(a[i], b[j], acc[i][j], 0, 0, 0);
    }

    #pragma unroll
    for (int i = 0; i < IF; ++i)
        #pragma unroll
        for (int q = 0; q < 4; ++q) {
            int row = m0 + rb + i * 16 + kg * 4 + q;
            if (row < M) {
                #pragma unroll
                for (int j = 0; j < 4; ++j)
                    C[(size_t)row * BN + cb + j * 16 + ln] = f2bf(acc[i][j][q]);
            }
        }
}

// ---- CSR build -------------------------------------------------------------
// Coarse buckets of 512 dst nodes. NCB = ceil(N/512) <= 256.

// LDS-privatized coarse histogram.
__global__ __launch_bounds__(256) void chist_kernel(const int* __restrict__ dst,
                                                    int* __restrict__ chist, int E) {
    __shared__ int h[256];
    h[threadIdx.x] = 0;
    __syncthreads();
    int stride = gridDim.x * 256;
    for (int i = blockIdx.x * 256 + threadIdx.x; i < E; i += stride)
        atomicAdd(&h[dst[i] >> 9], 1);
    __syncthreads();
    int v = h[threadIdx.x];
    if (v) atomicAdd(&chist[threadIdx.x], v);
}

// Single-block exclusive scan -> bucket offsets (cofs) + binA cursors (ccur).
__global__ __launch_bounds__(256) void cscan_kernel(const int* __restrict__ chist,
                                                    int* __restrict__ cofs,
                                                    int* __restrict__ ccur) {
    __shared__ int s[256];
    int tid = threadIdx.x;
    int v = chist[tid];
    s[tid] = v;
    __syncthreads();
    #pragma unroll
    for (int off = 1; off < 256; off <<= 1) {
        int t = (tid >= off) ? s[tid - off] : 0;
        __syncthreads();
        s[tid] += t;
        __syncthreads();
    }
    int excl = s[tid] - v;
    cofs[tid] = excl;
    ccur[tid] = excl;
    if (tid == 255) cofs[256] = s[255];   // = E
}

// binA: LDS counting-sort of 4096-edge chunks into coarse buckets,
// grouped coalesced writes into globally reserved ranges.
__global__ __launch_bounds__(256) void binA_kernel(const int* __restrict__ src,
                                                   const int* __restrict__ dst,
                                                   const float* __restrict__ ew,
                                                   int* __restrict__ ccur,
                                                   uint2* __restrict__ ebuf, int E) {
    __shared__ int lh[256];
    __shared__ int loff[256];
    __shared__ int gpos[256];
    __shared__ uint2 stage[4096];
    __shared__ unsigned char sbuck[4096];
    const int tid = threadIdx.x;
    const int base = blockIdx.x * 4096;
    const int nn = min(4096, E - base);

    lh[tid] = 0;
    __syncthreads();

    uint pk[16], wb[16];
    short bk[16], rk[16];
    #pragma unroll
    for (int i = 0; i < 16; ++i) {
        int li = tid + i * 256;
        bk[i] = -1;
        if (li < nn) {
            int e = base + li;
            int d = dst[e];
            int b = d >> 9;
            pk[i] = (uint)src[e] | ((uint)(d & 511) << 17);
            wb[i] = __float_as_uint(ew[e]);
            bk[i] = (short)b;
            rk[i] = (short)atomicAdd(&lh[b], 1);
        }
    }
    __syncthreads();

    int v = lh[tid];
    loff[tid] = v;
    __syncthreads();
    #pragma unroll
    for (int off = 1; off < 256; off <<= 1) {
        int t = (tid >= off) ? loff[tid - off] : 0;
        __syncthreads();
        loff[tid] += t;
        __syncthreads();
    }
    int excl = loff[tid] - v;
    __syncthreads();
    loff[tid] = excl;
    gpos[tid] = (v > 0) ? atomicAdd(&ccur[tid], v) : 0;
    __syncthreads();

    #pragma unroll
    for (int i = 0; i < 16; ++i)
        if (bk[i] >= 0) {
            int s = loff[bk[i]] + rk[i];
            stage[s] = make_uint2(pk[i], wb[i]);
            sbuck[s] = (unsigned char)bk[i];
        }
    __syncthreads();

    for (int s = tid; s < nn; s += 256) {
        uint2 e2 = stage[s];
        int b = sbuck[s];
        ebuf[gpos[b] + (s - loff[b])] = e2;
    }
}

// binB: one block per coarse bucket. Pass 0: LDS fine-histogram + scan ->
// writes rowptr slice. Pass 1: exact CSR placement (L2-local window).
__global__ __launch_bounds__(512) void binB_kernel(const uint2* __restrict__ ebuf,
                                                   const int* __restrict__ cofs,
                                                   int* __restrict__ rowptr,
                                                   int2* __restrict__ csr, int N) {
    __shared__ int fh[512];
    __shared__ int cur[512];
    const int c = blockIdx.x;
    const int tid = threadIdx.x;
    const int n0 = c << 9;
    const int cbase = cofs[c];
    const int cend = cofs[c + 1];

    fh[tid] = 0;
    __syncthreads();
    for (int e = cbase + tid; e < cend; e += 512)
        atomicAdd(&fh[ebuf[e].x >> 17], 1);
    __syncthreads();

    int v = fh[tid];
    __syncthreads();
    #pragma unroll
    for (int off = 1; off < 512; off <<= 1) {
        int t = (tid >= off) ? fh[tid - off] : 0;
        __syncthreads();
        fh[tid] += t;
        __syncthreads();
    }
    int r = cbase + fh[tid] - v;   // exclusive position
    if (n0 + tid <= N) rowptr[n0 + tid] = r;
    cur[tid] = r;
    __syncthreads();

    for (int e = cbase + tid; e < cend; e += 512) {
        uint2 u = ebuf[e];
        int fine = u.x >> 17;
        int pos = atomicAdd(&cur[fine], 1);
        csr[pos] = make_int2((int)(u.x & 0x1FFFF), (int)u.y);
    }
}

// ---- Aggregation: one wave per dst node, 16-deep gather pipeline -----------

__device__ __forceinline__ void load8_128(const int2* __restrict__ csr, int j,
                                          const ushort* rp, uint* v, float* w) {
    #pragma unroll
    for (int t = 0; t < 8; ++t) {
        int2 e = csr[j + t];
        v[t] = *(const uint*)(rp + (size_t)e.x * 128);
        w[t] = __int_as_float(e.y);
    }
}
__device__ __forceinline__ void fma8_128(const uint* v, const float* w,
                                         float& ax, float& ay) {
    #pragma unroll
    for (int t = 0; t < 8; ++t) {
        ax = fmaf(bf_lo(v[t]), w[t], ax);
        ay = fmaf(bf_hi(v[t]), w[t], ay);
    }
}
__device__ __forceinline__ void load8_64(const int2* __restrict__ csr, int j,
                                         const ushort* rp, uint* v, float* w) {
    #pragma unroll
    for (int t = 0; t < 8; ++t) {
        int2 e = csr[j + t];
        v[t] = (uint)rp[(size_t)e.x * 64];
        w[t] = __int_as_float(e.y);
    }
}
__device__ __forceinline__ void fma8_64(const uint* v, const float* w, float& a0) {
    #pragma unroll
    for (int t = 0; t < 8; ++t)
        a0 = fmaf(__uint_as_float(v[t] << 16), w[t], a0);
}

template <int F, bool OBF>
__global__ __launch_bounds__(256) void agg_kernel(const ushort* __restrict__ sup,
                                                  const int* __restrict__ rowptr,
                                                  const int2* __restrict__ csr,
                                                  const float* __restrict__ bias,
                                                  void* __restrict__ outp, int N) {
    int wid = (blockIdx.x * 256 + threadIdx.x) >> 6;
    int lane = threadIdx.x & 63;
    if (wid >= N) return;
    const int start = __builtin_amdgcn_readfirstlane(rowptr[wid]);
    const int end   = __builtin_amdgcn_readfirstlane(rowptr[wid + 1]);

    if (F == 128) {
        float ax = 0.f, ay = 0.f;
        const ushort* rp = sup + lane * 2;
        uint va[8], vb[8];
        float wa[8], wb[8];
        int j = start;
        for (; j + 16 <= end; j += 16) {
            load8_128(csr, j, rp, va, wa);
            load8_128(csr, j + 8, rp, vb, wb);
            fma8_128(va, wa, ax, ay);
            fma8_128(vb, wb, ax, ay);
        }
        for (; j + 8 <= end; j += 8) {
            load8_128(csr, j, rp, va, wa);
            fma8_128(va, wa, ax, ay);
        }
        for (; j < end; ++j) {
            int2 e = csr[j];
            float w = __int_as_float(e.y);
            uint v = *(const uint*)(rp + (size_t)e.x * 128);
            ax = fmaf(bf_lo(v), w, ax);
            ay = fmaf(bf_hi(v), w, ay);
        }
        ax = fmaxf(ax + bias[lane * 2 + 0], 0.f);
        ay = fmaxf(ay + bias[lane * 2 + 1], 0.f);
        if (OBF) {
            ((uint*)outp)[(size_t)wid * 64 + lane] =
                (uint)f2bf(ax) | ((uint)f2bf(ay) << 16);
        } else {
            ((float2*)outp)[(size_t)wid * 64 + lane] = make_float2(ax, ay);
        }
    } else {  // F == 64
        float a0 = 0.f;
        const ushort* rp = sup + lane;
        uint va[8], vb[8];
        float wa[8], wb[8];
        int j = start;
        for (; j + 16 <= end; j += 16) {
            load8_64(csr, j, rp, va, wa);
            load8_64(csr, j + 8, rp, vb, wb);
            fma8_64(va, wa, a0);
            fma8_64(vb, wb, a0);
        }
        for (; j + 8 <= end; j += 8) {
            load8_64(csr, j, rp, va, wa);
            fma8_64(va, wa, a0);
        }
        for (; j < end; ++j) {
            int2 e = csr[j];
            uint v = (uint)rp[(size_t)e.x * 64];
            a0 = fmaf(__uint_as_float(v << 16), __int_as_float(e.y), a0);
        }
        ((float*)outp)[(size_t)wid * 64 + lane] = fmaxf(a0 + bias[lane], 0.f);
    }
}

extern "C" void kernel_launch(void* const* d_in, const int* in_sizes, int n_in,
                              void* d_out, int out_size, void* d_ws, size_t ws_size,
                              hipStream_t stream) {
    const float* x  = (const float*)d_in[0];
    const int*   ei = (const int*)d_in[1];
    const float* ew = (const float*)d_in[2];
    const float* W1 = (const float*)d_in[3];
    const float* b1 = (const float*)d_in[4];
    const float* W2 = (const float*)d_in[5];
    const float* b2 = (const float*)d_in[6];
    float* out = (float*)d_out;

    const int N = in_sizes[0] / 128;     // 100000
    const int E = in_sizes[2];           // 1600000
    const int* src = ei;
    const int* dst = ei + E;
    const int NCB = (N + 511) / 512;     // 196 coarse buckets (<= 256)

    char* ws = (char*)d_ws;
    size_t o = 0;
    ushort* S      = (ushort*)(ws + o); o += (size_t)N * 128 * sizeof(ushort);
    ushort* H1b    = (ushort*)(ws + o); o += (size_t)N * 128 * sizeof(ushort);
    uint2*  ebuf   = (uint2*) (ws + o); o += (size_t)E * sizeof(uint2);
    int2*   csr    = (int2*)  (ws + o); o += (size_t)E * sizeof(int2);
    int*    rowptr = (int*)   (ws + o); o += (size_t)(N + 1) * sizeof(int);
    int*    chist  = (int*)   (ws + o); o += 256 * sizeof(int);
    int*    cofs   = (int*)   (ws + o); o += 257 * sizeof(int);
    int*    ccur   = (int*)   (ws + o); o += 256 * sizeof(int);
    ushort* Wt1    = (ushort*)(ws + o); o += 128 * 128 * sizeof(ushort);
    ushort* Wt2    = (ushort*)(ws + o); o += 128 * 64 * sizeof(ushort);

    // ---- weights -> transposed bf16 (one launch) ----
    wconv_kernel<<<96, 256, 0, stream>>>(W1, Wt1, W2, Wt2);

    // ---- CSR build ----
    hipMemsetAsync(chist, 0, 256 * sizeof(int), stream);
    chist_kernel<<<1024, 256, 0, stream>>>(dst, chist, E);
    cscan_kernel<<<1, 256, 0, stream>>>(chist, cofs, ccur);
    binA_kernel<<<(E + 4095) / 4096, 256, 0, stream>>>(src, dst, ew, ccur, ebuf, E);
    binB_kernel<<<NCB, 512, 0, stream>>>(ebuf, cofs, rowptr, csr, N);

    const int GB = (N + 127) / 128;

    // ---- layer 1 ----
    gemm_mfma<128, false><<<GB, 256, 0, stream>>>(x, Wt1, S, N);
    agg_kernel<128, true><<<(N + 3) / 4, 256, 0, stream>>>(S, rowptr, csr, b1, H1b, N);

    // ---- layer 2 ----
    gemm_mfma<64, true><<<GB, 256, 0, stream>>>(H1b, Wt2, S, N);
    agg_kernel<64, false><<<(N + 3) / 4, 256, 0, stream>>>(S, rowptr, csr, b2, out, N);
}

// Round 7
// 220.767 us; speedup vs baseline: 7.9907x; 1.0911x over previous
//
#include <hip/hip_runtime.h>

// ---------------------------------------------------------------------------
// GCN forward. Coarse-binned padded-CSR build + bf16 MFMA GEMMs +
// pair-wide (2 edges / load instr) gather aggregation, tail-free rows.
//   h1 = relu(segsum(ew * (x@W1)[src] -> dst) + b1)    128 -> 128
//   h2 = relu(segsum(ew * (h1@W2)[src] -> dst) + b2)   128 -> 64
// ---------------------------------------------------------------------------

typedef __attribute__((ext_vector_type(8))) short bf16x8;
typedef __attribute__((ext_vector_type(4))) float f32x4;

__device__ __forceinline__ ushort f2bf(float f) {
    uint u = __float_as_uint(f);
    u += 0x7fff + ((u >> 16) & 1);   // round-to-nearest-even
    return (ushort)(u >> 16);
}
__device__ __forceinline__ float bf_lo(uint bits) { return __uint_as_float(bits << 16); }
__device__ __forceinline__ float bf_hi(uint bits) { return __uint_as_float(bits & 0xffff0000u); }

// ---- W1,W2 -> bf16 transposed [n][k] (single launch) -----------------------
__global__ __launch_bounds__(256) void wconv_kernel(const float* __restrict__ W1,
                                                    ushort* __restrict__ Wt1,
                                                    const float* __restrict__ W2,
                                                    ushort* __restrict__ Wt2) {
    int i = blockIdx.x * 256 + threadIdx.x;
    if (i < 128 * 128) {
        int k = i >> 7, n = i & 127;
        Wt1[n * 128 + k] = f2bf(W1[i]);
    } else {
        int i2 = i - 128 * 128;
        if (i2 < 128 * 64) {
            int k = i2 >> 6, n = i2 & 63;
            Wt2[n * 128 + k] = f2bf(W2[i2]);
        }
    }
}

// ---- GEMM: C[M,BN](bf16) = A[M,128] * W[128,BN] ----------------------------
template <int BN, bool ABF16>
__global__ __launch_bounds__(256) void gemm_mfma(const void* __restrict__ Av,
                                                 const ushort* __restrict__ Wt,
                                                 ushort* __restrict__ C, int M) {
    __shared__ ushort As[128 * 128];
    const int tid = threadIdx.x;
    const int m0 = blockIdx.x * 128;

    #pragma unroll
    for (int it = 0; it < 8; ++it) {
        int c = tid + it * 256;
        int r = c >> 4;
        int k8 = (c & 15) << 3;
        int row = m0 + r;
        uint4 w4 = make_uint4(0u, 0u, 0u, 0u);
        if (row < M) {
            if (ABF16) {
                w4 = *(const uint4*)((const ushort*)Av + (size_t)row * 128 + k8);
            } else {
                const float* A = (const float*)Av;
                float4 v0 = *(const float4*)(A + (size_t)row * 128 + k8);
                float4 v1 = *(const float4*)(A + (size_t)row * 128 + k8 + 4);
                w4.x = (uint)f2bf(v0.x) | ((uint)f2bf(v0.y) << 16);
                w4.y = (uint)f2bf(v0.z) | ((uint)f2bf(v0.w) << 16);
                w4.z = (uint)f2bf(v1.x) | ((uint)f2bf(v1.y) << 16);
                w4.w = (uint)f2bf(v1.z) | ((uint)f2bf(v1.w) << 16);
            }
        }
        int byte = (r * 256 + k8 * 2) ^ ((r & 7) << 4);
        *(uint4*)((char*)As + byte) = w4;
    }
    __syncthreads();

    const int wid = tid >> 6, lane = tid & 63;
    constexpr int IF = (BN == 128) ? 4 : 2;
    const int wy = (BN == 128) ? (wid >> 1) : wid;
    const int wx = (BN == 128) ? (wid & 1) : 0;
    const int rb = wy * 16 * IF;
    const int cb = wx * 64;
    const int ln = lane & 15;
    const int kg = lane >> 4;

    f32x4 acc[IF][4];
    #pragma unroll
    for (int i = 0; i < IF; ++i)
        #pragma unroll
        for (int j = 0; j < 4; ++j) acc[i][j] = (f32x4){0.f, 0.f, 0.f, 0.f};

    #pragma unroll
    for (int s = 0; s < 4; ++s) {
        bf16x8 b[4];
        #pragma unroll
        for (int j = 0; j < 4; ++j)
            b[j] = *(const bf16x8*)(Wt + (size_t)(cb + j * 16 + ln) * 128 + s * 32 + kg * 8);
        bf16x8 a[IF];
        #pragma unroll
        for (int i = 0; i < IF; ++i) {
            int r = rb + i * 16 + ln;
            int byte = (r * 256 + s * 64 + kg * 16) ^ ((r & 7) << 4);
            a[i] = *(const bf16x8*)((const char*)As + byte);
        }
        #pragma unroll
        for (int i = 0; i < IF; ++i)
            #pragma unroll
            for (int j = 0; j < 4; ++j)
                acc[i][j] = __builtin_amdgcn_mfma_f32_16x16x32_bf16(a[i], b[j], acc[i][j], 0, 0, 0);
    }

    #pragma unroll
    for (int i = 0; i < IF; ++i)
        #pragma unroll
        for (int q = 0; q < 4; ++q) {
            int row = m0 + rb + i * 16 + kg * 4 + q;
            if (row < M) {
                #pragma unroll
                for (int j = 0; j < 4; ++j)
                    C[(size_t)row * BN + cb + j * 16 + ln] = f2bf(acc[i][j][q]);
            }
        }
}

// ---- CSR build -------------------------------------------------------------
// Coarse buckets of 512 dst nodes; per-node rows padded to multiple of 16
// with (src=0, w=0) dummies so agg loops are tail-free.

__global__ __launch_bounds__(256) void chist_kernel(const int* __restrict__ dst,
                                                    int* __restrict__ chist, int E) {
    __shared__ int h[256];
    h[threadIdx.x] = 0;
    __syncthreads();
    int stride = gridDim.x * 256;
    for (int i = blockIdx.x * 256 + threadIdx.x; i < E; i += stride)
        atomicAdd(&h[dst[i] >> 9], 1);
    __syncthreads();
    int v = h[threadIdx.x];
    if (v) atomicAdd(&chist[threadIdx.x], v);
}

__global__ __launch_bounds__(256) void cscan_kernel(const int* __restrict__ chist,
                                                    int* __restrict__ cofs,
                                                    int* __restrict__ ccur) {
    __shared__ int s[256];
    int tid = threadIdx.x;
    int v = chist[tid];
    s[tid] = v;
    __syncthreads();
    #pragma unroll
    for (int off = 1; off < 256; off <<= 1) {
        int t = (tid >= off) ? s[tid - off] : 0;
        __syncthreads();
        s[tid] += t;
        __syncthreads();
    }
    int excl = s[tid] - v;
    cofs[tid] = excl;
    ccur[tid] = excl;
    if (tid == 255) cofs[256] = s[255];   // = E
}

// binA: LDS counting-sort of 4096-edge chunks into coarse buckets,
// grouped coalesced writes into globally reserved ranges.
__global__ __launch_bounds__(256) void binA_kernel(const int* __restrict__ src,
                                                   const int* __restrict__ dst,
                                                   const float* __restrict__ ew,
                                                   int* __restrict__ ccur,
                                                   uint2* __restrict__ ebuf, int E) {
    __shared__ int lh[256];
    __shared__ int loff[256];
    __shared__ int gpos[256];
    __shared__ uint2 stage[4096];
    __shared__ unsigned char sbuck[4096];
    const int tid = threadIdx.x;
    const int base = blockIdx.x * 4096;
    const int nn = min(4096, E - base);

    lh[tid] = 0;
    __syncthreads();

    uint pk[16], wb[16];
    short bk[16], rk[16];
    #pragma unroll
    for (int i = 0; i < 16; ++i) {
        int li = tid + i * 256;
        bk[i] = -1;
        if (li < nn) {
            int e = base + li;
            int d = dst[e];
            int b = d >> 9;
            pk[i] = (uint)src[e] | ((uint)(d & 511) << 17);
            wb[i] = __float_as_uint(ew[e]);
            bk[i] = (short)b;
            rk[i] = (short)atomicAdd(&lh[b], 1);
        }
    }
    __syncthreads();

    int v = lh[tid];
    loff[tid] = v;
    __syncthreads();
    #pragma unroll
    for (int off = 1; off < 256; off <<= 1) {
        int t = (tid >= off) ? loff[tid - off] : 0;
        __syncthreads();
        loff[tid] += t;
        __syncthreads();
    }
    int excl = loff[tid] - v;
    __syncthreads();
    loff[tid] = excl;
    gpos[tid] = (v > 0) ? atomicAdd(&ccur[tid], v) : 0;
    __syncthreads();

    #pragma unroll
    for (int i = 0; i < 16; ++i)
        if (bk[i] >= 0) {
            int s = loff[bk[i]] + rk[i];
            stage[s] = make_uint2(pk[i], wb[i]);
            sbuck[s] = (unsigned char)bk[i];
        }
    __syncthreads();

    for (int s = tid; s < nn; s += 256) {
        uint2 e2 = stage[s];
        int b = sbuck[s];
        ebuf[gpos[b] + (s - loff[b])] = e2;
    }
}

// binB: one block per coarse bucket. Fine-histogram + padded scan ->
// rstart/pdeg; exact placement; dummy fill. All in bucket-local L2 window.
#define PADCAP 8192   // 512 nodes * 16 max pad
__global__ __launch_bounds__(512) void binB_kernel(const uint2* __restrict__ ebuf,
                                                   const int* __restrict__ cofs,
                                                   int* __restrict__ rstart,
                                                   int* __restrict__ pdeg,
                                                   int2* __restrict__ csr, int N) {
    __shared__ int fh[512];
    __shared__ int pp[512];
    __shared__ int cur[512];
    const int c = blockIdx.x;
    const int tid = threadIdx.x;
    const int n0 = c << 9;
    const int cbase = cofs[c];
    const int cend = cofs[c + 1];
    const int pbase = cbase + c * PADCAP;

    fh[tid] = 0;
    __syncthreads();
    for (int e = cbase + tid; e < cend; e += 512)
        atomicAdd(&fh[ebuf[e].x >> 17], 1);
    __syncthreads();

    int cnt = fh[tid];
    int p = (cnt + 15) & ~15;
    pp[tid] = p;
    __syncthreads();
    #pragma unroll
    for (int off = 1; off < 512; off <<= 1) {
        int t = (tid >= off) ? pp[tid - off] : 0;
        __syncthreads();
        pp[tid] += t;
        __syncthreads();
    }
    int r = pbase + pp[tid] - p;   // padded exclusive position
    if (n0 + tid < N) {
        rstart[n0 + tid] = r;
        pdeg[n0 + tid] = p;
    }
    cur[tid] = r;
    __syncthreads();

    for (int e = cbase + tid; e < cend; e += 512) {
        uint2 u = ebuf[e];
        int fine = u.x >> 17;
        int pos = atomicAdd(&cur[fine], 1);
        csr[pos] = make_int2((int)(u.x & 0x1FFFF), (int)u.y);
    }
    __syncthreads();

    // dummy fill (src=0, w=0) up to padded end
    for (int k = cur[tid]; k < r + p; ++k)
        csr[k] = make_int2(0, 0);
}

// ---- Aggregation: one wave per dst node, 2 edges per load instruction ------
// Half-wave (32 lanes) covers one support row; rows padded to 16 edges.

template <int F, bool OBF>
__global__ __launch_bounds__(256) void agg_kernel(const ushort* __restrict__ sup,
                                                  const int* __restrict__ rstart,
                                                  const int* __restrict__ pdeg,
                                                  const int2* __restrict__ csr,
                                                  const float* __restrict__ bias,
                                                  void* __restrict__ outp, int N) {
    int wid = (blockIdx.x * 256 + threadIdx.x) >> 6;
    int lane = threadIdx.x & 63;
    if (wid >= N) return;
    const int start = __builtin_amdgcn_readfirstlane(rstart[wid]);
    const int p     = __builtin_amdgcn_readfirstlane(pdeg[wid]);
    const int end = start + p;
    const bool hi = (lane >> 5) != 0;
    const int cl = lane & 31;

    if (F == 128) {
        const ushort* rp = sup + cl * 4;       // 8B chunk cl of a 256B row
        float a0 = 0.f, a1 = 0.f, a2 = 0.f, a3 = 0.f;
        uint2 v[8];
        float w[8];
        for (int j = start; j < end; j += 16) {
            #pragma unroll
            for (int t = 0; t < 8; ++t) {
                int2 eA = csr[j + 2 * t];
                int2 eB = csr[j + 2 * t + 1];
                int s = hi ? eB.x : eA.x;
                w[t] = __int_as_float(hi ? eB.y : eA.y);
                v[t] = *(const uint2*)(rp + (size_t)s * 128);
            }
            #pragma unroll
            for (int t = 0; t < 8; ++t) {
                float wt = w[t];
                a0 = fmaf(bf_lo(v[t].x), wt, a0);
                a1 = fmaf(bf_hi(v[t].x), wt, a1);
                a2 = fmaf(bf_lo(v[t].y), wt, a2);
                a3 = fmaf(bf_hi(v[t].y), wt, a3);
            }
        }
        a0 += __shfl_xor(a0, 32);
        a1 += __shfl_xor(a1, 32);
        a2 += __shfl_xor(a2, 32);
        a3 += __shfl_xor(a3, 32);
        if (lane < 32) {
            float4 bv = ((const float4*)bias)[cl];
            a0 = fmaxf(a0 + bv.x, 0.f);
            a1 = fmaxf(a1 + bv.y, 0.f);
            a2 = fmaxf(a2 + bv.z, 0.f);
            a3 = fmaxf(a3 + bv.w, 0.f);
            if (OBF) {
                uint2 o;
                o.x = (uint)f2bf(a0) | ((uint)f2bf(a1) << 16);
                o.y = (uint)f2bf(a2) | ((uint)f2bf(a3) << 16);
                ((uint2*)outp)[(size_t)wid * 32 + cl] = o;
            } else {
                ((float4*)outp)[(size_t)wid * 32 + cl] = make_float4(a0, a1, a2, a3);
            }
        }
    } else {  // F == 64, row = 128B
        const ushort* rp = sup + cl * 2;       // 4B chunk cl of a 128B row
        float a0 = 0.f, a1 = 0.f;
        uint v16[16];
        float w16[16];
        int j = start;
        for (; j + 32 <= end; j += 32) {
            #pragma unroll
            for (int t = 0; t < 16; ++t) {
                int2 eA = csr[j + 2 * t];
                int2 eB = csr[j + 2 * t + 1];
                int s = hi ? eB.x : eA.x;
                w16[t] = __int_as_float(hi ? eB.y : eA.y);
                v16[t] = *(const uint*)(rp + (size_t)s * 64);
            }
            #pragma unroll
            for (int t = 0; t < 16; ++t) {
                a0 = fmaf(bf_lo(v16[t]), w16[t], a0);
                a1 = fmaf(bf_hi(v16[t]), w16[t], a1);
            }
        }
        if (j < end) {  // exactly 16 edges remain
            #pragma unroll
            for (int t = 0; t < 8; ++t) {
                int2 eA = csr[j + 2 * t];
                int2 eB = csr[j + 2 * t + 1];
                int s = hi ? eB.x : eA.x;
                w16[t] = __int_as_float(hi ? eB.y : eA.y);
                v16[t] = *(const uint*)(rp + (size_t)s * 64);
            }
            #pragma unroll
            for (int t = 0; t < 8; ++t) {
                a0 = fmaf(bf_lo(v16[t]), w16[t], a0);
                a1 = fmaf(bf_hi(v16[t]), w16[t], a1);
            }
        }
        a0 += __shfl_xor(a0, 32);
        a1 += __shfl_xor(a1, 32);
        if (lane < 32) {
            float2 bv = ((const float2*)bias)[cl];
            a0 = fmaxf(a0 + bv.x, 0.f);
            a1 = fmaxf(a1 + bv.y, 0.f);
            ((float2*)outp)[(size_t)wid * 32 + cl] = make_float2(a0, a1);
        }
    }
}

extern "C" void kernel_launch(void* const* d_in, const int* in_sizes, int n_in,
                              void* d_out, int out_size, void* d_ws, size_t ws_size,
                              hipStream_t stream) {
    const float* x  = (const float*)d_in[0];
    const int*   ei = (const int*)d_in[1];
    const float* ew = (const float*)d_in[2];
    const float* W1 = (const float*)d_in[3];
    const float* b1 = (const float*)d_in[4];
    const float* W2 = (const float*)d_in[5];
    const float* b2 = (const float*)d_in[6];
    float* out = (float*)d_out;

    const int N = in_sizes[0] / 128;     // 100000
    const int E = in_sizes[2];           // 1600000
    const int* src = ei;
    const int* dst = ei + E;
    const int NCB = (N + 511) / 512;     // 196 coarse buckets (<= 256)

    char* ws = (char*)d_ws;
    size_t o = 0;
    ushort* S      = (ushort*)(ws + o); o += (size_t)N * 128 * sizeof(ushort);
    ushort* H1b    = (ushort*)(ws + o); o += (size_t)N * 128 * sizeof(ushort);
    uint2*  ebuf   = (uint2*) (ws + o); o += (size_t)E * sizeof(uint2);
    int2*   csr    = (int2*)  (ws + o); o += ((size_t)E + (size_t)NCB * PADCAP) * sizeof(int2);
    int*    rstart = (int*)   (ws + o); o += (size_t)N * sizeof(int);
    int*    pdeg   = (int*)   (ws + o); o += (size_t)N * sizeof(int);
    int*    chist  = (int*)   (ws + o); o += 256 * sizeof(int);
    int*    cofs   = (int*)   (ws + o); o += 257 * sizeof(int);
    int*    ccur   = (int*)   (ws + o); o += 256 * sizeof(int);
    ushort* Wt1    = (ushort*)(ws + o); o += 128 * 128 * sizeof(ushort);
    ushort* Wt2    = (ushort*)(ws + o); o += 128 * 64 * sizeof(ushort);

    // ---- weights -> transposed bf16 ----
    wconv_kernel<<<96, 256, 0, stream>>>(W1, Wt1, W2, Wt2);

    // ---- CSR build ----
    hipMemsetAsync(chist, 0, 256 * sizeof(int), stream);
    chist_kernel<<<1024, 256, 0, stream>>>(dst, chist, E);
    cscan_kernel<<<1, 256, 0, stream>>>(chist, cofs, ccur);
    binA_kernel<<<(E + 4095) / 4096, 256, 0, stream>>>(src, dst, ew, ccur, ebuf, E);
    binB_kernel<<<NCB, 512, 0, stream>>>(ebuf, cofs, rstart, pdeg, csr, N);

    const int GB = (N + 127) / 128;

    // ---- layer 1 ----
    gemm_mfma<128, false><<<GB, 256, 0, stream>>>(x, Wt1, S, N);
    agg_kernel<128, true><<<(N + 3) / 4, 256, 0, stream>>>(S, rstart, pdeg, csr, b1, H1b, N);

    // ---- layer 2 ----
    gemm_mfma<64, true><<<GB, 256, 0, stream>>>(H1b, Wt2, S, N);
    agg_kernel<64, false><<<(N + 3) / 4, 256, 0, stream>>>(S, rstart, pdeg, csr, b2, out, N);
}

// Round 8
// 210.902 us; speedup vs baseline: 8.3644x; 1.0468x over previous
//
#include <hip/hip_runtime.h>

// ---------------------------------------------------------------------------
// GCN forward. Coarse-binned padded-CSR build + bf16 MFMA GEMMs +
// uint4 multi-edge-per-instruction gather aggregation (pad-8, tail-free).
//   h1 = relu(segsum(ew * (x@W1)[src] -> dst) + b1)    128 -> 128
//   h2 = relu(segsum(ew * (h1@W2)[src] -> dst) + b2)   128 -> 64
// ---------------------------------------------------------------------------

typedef __attribute__((ext_vector_type(8))) short bf16x8;
typedef __attribute__((ext_vector_type(4))) float f32x4;

__device__ __forceinline__ ushort f2bf(float f) {
    uint u = __float_as_uint(f);
    u += 0x7fff + ((u >> 16) & 1);   // round-to-nearest-even
    return (ushort)(u >> 16);
}
__device__ __forceinline__ float bf_lo(uint bits) { return __uint_as_float(bits << 16); }
__device__ __forceinline__ float bf_hi(uint bits) { return __uint_as_float(bits & 0xffff0000u); }

// ---- GEMM: C[M,BN](bf16) = A[M,128] * W[128,BN] ----------------------------
template <int BN, bool ABF16>
__global__ __launch_bounds__(256) void gemm_mfma(const void* __restrict__ Av,
                                                 const ushort* __restrict__ Wt,
                                                 ushort* __restrict__ C, int M) {
    __shared__ ushort As[128 * 128];
    const int tid = threadIdx.x;
    const int m0 = blockIdx.x * 128;

    #pragma unroll
    for (int it = 0; it < 8; ++it) {
        int c = tid + it * 256;
        int r = c >> 4;
        int k8 = (c & 15) << 3;
        int row = m0 + r;
        uint4 w4 = make_uint4(0u, 0u, 0u, 0u);
        if (row < M) {
            if (ABF16) {
                w4 = *(const uint4*)((const ushort*)Av + (size_t)row * 128 + k8);
            } else {
                const float* A = (const float*)Av;
                float4 v0 = *(const float4*)(A + (size_t)row * 128 + k8);
                float4 v1 = *(const float4*)(A + (size_t)row * 128 + k8 + 4);
                w4.x = (uint)f2bf(v0.x) | ((uint)f2bf(v0.y) << 16);
                w4.y = (uint)f2bf(v0.z) | ((uint)f2bf(v0.w) << 16);
                w4.z = (uint)f2bf(v1.x) | ((uint)f2bf(v1.y) << 16);
                w4.w = (uint)f2bf(v1.z) | ((uint)f2bf(v1.w) << 16);
            }
        }
        int byte = (r * 256 + k8 * 2) ^ ((r & 7) << 4);
        *(uint4*)((char*)As + byte) = w4;
    }
    __syncthreads();

    const int wid = tid >> 6, lane = tid & 63;
    constexpr int IF = (BN == 128) ? 4 : 2;
    const int wy = (BN == 128) ? (wid >> 1) : wid;
    const int wx = (BN == 128) ? (wid & 1) : 0;
    const int rb = wy * 16 * IF;
    const int cb = wx * 64;
    const int ln = lane & 15;
    const int kg = lane >> 4;

    f32x4 acc[IF][4];
    #pragma unroll
    for (int i = 0; i < IF; ++i)
        #pragma unroll
        for (int j = 0; j < 4; ++j) acc[i][j] = (f32x4){0.f, 0.f, 0.f, 0.f};

    #pragma unroll
    for (int s = 0; s < 4; ++s) {
        bf16x8 b[4];
        #pragma unroll
        for (int j = 0; j < 4; ++j)
            b[j] = *(const bf16x8*)(Wt + (size_t)(cb + j * 16 + ln) * 128 + s * 32 + kg * 8);
        bf16x8 a[IF];
        #pragma unroll
        for (int i = 0; i < IF; ++i) {
            int r = rb + i * 16 + ln;
            int byte = (r * 256 + s * 64 + kg * 16) ^ ((r & 7) << 4);
            a[i] = *(const bf16x8*)((const char*)As + byte);
        }
        #pragma unroll
        for (int i = 0; i < IF; ++i)
            #pragma unroll
            for (int j = 0; j < 4; ++j)
                acc[i][j] = __builtin_amdgcn_mfma_f32_16x16x32_bf16(a[i], b[j], acc[i][j], 0, 0, 0);
    }

    #pragma unroll
    for (int i = 0; i < IF; ++i)
        #pragma unroll
        for (int q = 0; q < 4; ++q) {
            int row = m0 + rb + i * 16 + kg * 4 + q;
            if (row < M) {
                #pragma unroll
                for (int j = 0; j < 4; ++j)
                    C[(size_t)row * BN + cb + j * 16 + ln] = f2bf(acc[i][j][q]);
            }
        }
}

// ---- CSR build -------------------------------------------------------------
// Coarse buckets of 512 dst nodes; per-node rows padded to multiple of 8.

// chist + fused weight conversion (saves a dispatch).
__global__ __launch_bounds__(256) void chist_kernel(const int* __restrict__ dst,
                                                    int* __restrict__ chist, int E,
                                                    const float* __restrict__ W1,
                                                    ushort* __restrict__ Wt1,
                                                    const float* __restrict__ W2,
                                                    ushort* __restrict__ Wt2) {
    __shared__ int h[256];
    h[threadIdx.x] = 0;
    __syncthreads();
    int gi = blockIdx.x * 256 + threadIdx.x;
    if (gi < 128 * 128) {
        int k = gi >> 7, n = gi & 127;
        Wt1[n * 128 + k] = f2bf(W1[gi]);
    } else if (gi < 128 * 192) {
        int i2 = gi - 128 * 128;
        int k = i2 >> 6, n = i2 & 63;
        Wt2[n * 128 + k] = f2bf(W2[i2]);
    }
    int stride = gridDim.x * 256;
    for (int i = gi; i < E; i += stride)
        atomicAdd(&h[dst[i] >> 9], 1);
    __syncthreads();
    int v = h[threadIdx.x];
    if (v) atomicAdd(&chist[threadIdx.x], v);
}

__global__ __launch_bounds__(256) void cscan_kernel(const int* __restrict__ chist,
                                                    int* __restrict__ cofs,
                                                    int* __restrict__ ccur) {
    __shared__ int s[256];
    int tid = threadIdx.x;
    int v = chist[tid];
    s[tid] = v;
    __syncthreads();
    #pragma unroll
    for (int off = 1; off < 256; off <<= 1) {
        int t = (tid >= off) ? s[tid - off] : 0;
        __syncthreads();
        s[tid] += t;
        __syncthreads();
    }
    int excl = s[tid] - v;
    cofs[tid] = excl;
    ccur[tid] = excl;
    if (tid == 255) cofs[256] = s[255];   // = E
}

// binA: LDS counting-sort of 4096-edge chunks into coarse buckets,
// grouped coalesced writes into globally reserved ranges.
__global__ __launch_bounds__(256) void binA_kernel(const int* __restrict__ src,
                                                   const int* __restrict__ dst,
                                                   const float* __restrict__ ew,
                                                   int* __restrict__ ccur,
                                                   uint2* __restrict__ ebuf, int E) {
    __shared__ int lh[256];
    __shared__ int loff[256];
    __shared__ int gpos[256];
    __shared__ uint2 stage[4096];
    __shared__ unsigned char sbuck[4096];
    const int tid = threadIdx.x;
    const int base = blockIdx.x * 4096;
    const int nn = min(4096, E - base);

    lh[tid] = 0;
    __syncthreads();

    uint pk[16], wb[16];
    short bk[16], rk[16];
    #pragma unroll
    for (int i = 0; i < 16; ++i) {
        int li = tid + i * 256;
        bk[i] = -1;
        if (li < nn) {
            int e = base + li;
            int d = dst[e];
            int b = d >> 9;
            pk[i] = (uint)src[e] | ((uint)(d & 511) << 17);
            wb[i] = __float_as_uint(ew[e]);
            bk[i] = (short)b;
            rk[i] = (short)atomicAdd(&lh[b], 1);
        }
    }
    __syncthreads();

    int v = lh[tid];
    loff[tid] = v;
    __syncthreads();
    #pragma unroll
    for (int off = 1; off < 256; off <<= 1) {
        int t = (tid >= off) ? loff[tid - off] : 0;
        __syncthreads();
        loff[tid] += t;
        __syncthreads();
    }
    int excl = loff[tid] - v;
    __syncthreads();
    loff[tid] = excl;
    gpos[tid] = (v > 0) ? atomicAdd(&ccur[tid], v) : 0;
    __syncthreads();

    #pragma unroll
    for (int i = 0; i < 16; ++i)
        if (bk[i] >= 0) {
            int s = loff[bk[i]] + rk[i];
            stage[s] = make_uint2(pk[i], wb[i]);
            sbuck[s] = (unsigned char)bk[i];
        }
    __syncthreads();

    for (int s = tid; s < nn; s += 256) {
        uint2 e2 = stage[s];
        int b = sbuck[s];
        ebuf[gpos[b] + (s - loff[b])] = e2;
    }
}

// binB: one block per coarse bucket. Fine-histogram + padded scan ->
// rstart/pdeg; exact placement; dummy fill. All in bucket-local L2 window.
#define PADCAP 4096   // 512 nodes * 8 max pad
__global__ __launch_bounds__(512) void binB_kernel(const uint2* __restrict__ ebuf,
                                                   const int* __restrict__ cofs,
                                                   int* __restrict__ rstart,
                                                   int* __restrict__ pdeg,
                                                   int2* __restrict__ csr, int N) {
    __shared__ int fh[512];
    __shared__ int pp[512];
    __shared__ int cur[512];
    const int c = blockIdx.x;
    const int tid = threadIdx.x;
    const int n0 = c << 9;
    const int cbase = cofs[c];
    const int cend = cofs[c + 1];
    const int pbase = cbase + c * PADCAP;

    fh[tid] = 0;
    __syncthreads();
    for (int e = cbase + tid; e < cend; e += 512)
        atomicAdd(&fh[ebuf[e].x >> 17], 1);
    __syncthreads();

    int cnt = fh[tid];
    int p = (cnt + 7) & ~7;          // pad rows to multiple of 8
    pp[tid] = p;
    __syncthreads();
    #pragma unroll
    for (int off = 1; off < 512; off <<= 1) {
        int t = (tid >= off) ? pp[tid - off] : 0;
        __syncthreads();
        pp[tid] += t;
        __syncthreads();
    }
    int r = pbase + pp[tid] - p;   // padded exclusive position
    if (n0 + tid < N) {
        rstart[n0 + tid] = r;
        pdeg[n0 + tid] = p;
    }
    cur[tid] = r;
    __syncthreads();

    for (int e = cbase + tid; e < cend; e += 512) {
        uint2 u = ebuf[e];
        int fine = u.x >> 17;
        int pos = atomicAdd(&cur[fine], 1);
        csr[pos] = make_int2((int)(u.x & 0x1FFFF), (int)u.y);
    }
    __syncthreads();

    // dummy fill (src=0, w=0) up to padded end
    for (int k = cur[tid]; k < r + p; ++k)
        csr[k] = make_int2(0, 0);
}

// ---- Aggregation: one wave per dst node ------------------------------------
// uint4 per lane (16B): F=128 -> 16 lanes/row, 4 edges/instr;
//                       F=64  ->  8 lanes/row, 8 edges/instr.
// Per-lane metadata loads (G x 8B contiguous = 1 line, broadcast in group).

template <int F, bool OBF>
__global__ __launch_bounds__(256) void agg_kernel(const ushort* __restrict__ sup,
                                                  const int* __restrict__ rstart,
                                                  const int* __restrict__ pdeg,
                                                  const int2* __restrict__ csr,
                                                  const float* __restrict__ bias,
                                                  void* __restrict__ outp, int N) {
    constexpr int LPR = F / 8;      // lanes per row (uint4 = 8 bf16)
    constexpr int G = 64 / LPR;     // edges per load instruction
    int wid = (blockIdx.x * 256 + threadIdx.x) >> 6;
    int lane = threadIdx.x & 63;
    if (wid >= N) return;
    const int start = __builtin_amdgcn_readfirstlane(rstart[wid]);
    const int p     = __builtin_amdgcn_readfirstlane(pdeg[wid]);
    const int end = start + p;
    const int grp = lane / LPR;
    const int cl  = lane % LPR;
    const ushort* rp = sup + cl * 8;

    float acc[8] = {0.f, 0.f, 0.f, 0.f, 0.f, 0.f, 0.f, 0.f};

    int j = start;
    for (; j + 4 * G <= end; j += 4 * G) {
        int2 m[4];
        #pragma unroll
        for (int t = 0; t < 4; ++t) m[t] = csr[j + t * G + grp];
        uint4 v[4];
        #pragma unroll
        for (int t = 0; t < 4; ++t) v[t] = *(const uint4*)(rp + (size_t)m[t].x * F);
        #pragma unroll
        for (int t = 0; t < 4; ++t) {
            float w = __int_as_float(m[t].y);
            uint4 u = v[t];
            acc[0] = fmaf(bf_lo(u.x), w, acc[0]); acc[1] = fmaf(bf_hi(u.x), w, acc[1]);
            acc[2] = fmaf(bf_lo(u.y), w, acc[2]); acc[3] = fmaf(bf_hi(u.y), w, acc[3]);
            acc[4] = fmaf(bf_lo(u.z), w, acc[4]); acc[5] = fmaf(bf_hi(u.z), w, acc[5]);
            acc[6] = fmaf(bf_lo(u.w), w, acc[6]); acc[7] = fmaf(bf_hi(u.w), w, acc[7]);
        }
    }
    for (; j + 2 * G <= end; j += 2 * G) {
        int2 m[2];
        #pragma unroll
        for (int t = 0; t < 2; ++t) m[t] = csr[j + t * G + grp];
        uint4 v[2];
        #pragma unroll
        for (int t = 0; t < 2; ++t) v[t] = *(const uint4*)(rp + (size_t)m[t].x * F);
        #pragma unroll
        for (int t = 0; t < 2; ++t) {
            float w = __int_as_float(m[t].y);
            uint4 u = v[t];
            acc[0] = fmaf(bf_lo(u.x), w, acc[0]); acc[1] = fmaf(bf_hi(u.x), w, acc[1]);
            acc[2] = fmaf(bf_lo(u.y), w, acc[2]); acc[3] = fmaf(bf_hi(u.y), w, acc[3]);
            acc[4] = fmaf(bf_lo(u.z), w, acc[4]); acc[5] = fmaf(bf_hi(u.z), w, acc[5]);
            acc[6] = fmaf(bf_lo(u.w), w, acc[6]); acc[7] = fmaf(bf_hi(u.w), w, acc[7]);
        }
    }
    for (; j + G <= end; j += G) {
        int2 m = csr[j + grp];
        uint4 u = *(const uint4*)(rp + (size_t)m.x * F);
        float w = __int_as_float(m.y);
        acc[0] = fmaf(bf_lo(u.x), w, acc[0]); acc[1] = fmaf(bf_hi(u.x), w, acc[1]);
        acc[2] = fmaf(bf_lo(u.y), w, acc[2]); acc[3] = fmaf(bf_hi(u.y), w, acc[3]);
        acc[4] = fmaf(bf_lo(u.z), w, acc[4]); acc[5] = fmaf(bf_hi(u.z), w, acc[5]);
        acc[6] = fmaf(bf_lo(u.w), w, acc[6]); acc[7] = fmaf(bf_hi(u.w), w, acc[7]);
    }

    #pragma unroll
    for (int off = 32; off >= LPR; off >>= 1)
        #pragma unroll
        for (int i = 0; i < 8; ++i) acc[i] += __shfl_xor(acc[i], off);

    if (lane < LPR) {
        float4 b0 = ((const float4*)bias)[cl * 2 + 0];
        float4 b1 = ((const float4*)bias)[cl * 2 + 1];
        acc[0] = fmaxf(acc[0] + b0.x, 0.f); acc[1] = fmaxf(acc[1] + b0.y, 0.f);
        acc[2] = fmaxf(acc[2] + b0.z, 0.f); acc[3] = fmaxf(acc[3] + b0.w, 0.f);
        acc[4] = fmaxf(acc[4] + b1.x, 0.f); acc[5] = fmaxf(acc[5] + b1.y, 0.f);
        acc[6] = fmaxf(acc[6] + b1.z, 0.f); acc[7] = fmaxf(acc[7] + b1.w, 0.f);
        if (OBF) {
            uint4 o;
            o.x = (uint)f2bf(acc[0]) | ((uint)f2bf(acc[1]) << 16);
            o.y = (uint)f2bf(acc[2]) | ((uint)f2bf(acc[3]) << 16);
            o.z = (uint)f2bf(acc[4]) | ((uint)f2bf(acc[5]) << 16);
            o.w = (uint)f2bf(acc[6]) | ((uint)f2bf(acc[7]) << 16);
            ((uint4*)outp)[(size_t)wid * LPR + cl] = o;
        } else {
            ((float4*)outp)[(size_t)wid * LPR * 2 + cl * 2 + 0] =
                make_float4(acc[0], acc[1], acc[2], acc[3]);
            ((float4*)outp)[(size_t)wid * LPR * 2 + cl * 2 + 1] =
                make_float4(acc[4], acc[5], acc[6], acc[7]);
        }
    }
}

extern "C" void kernel_launch(void* const* d_in, const int* in_sizes, int n_in,
                              void* d_out, int out_size, void* d_ws, size_t ws_size,
                              hipStream_t stream) {
    const float* x  = (const float*)d_in[0];
    const int*   ei = (const int*)d_in[1];
    const float* ew = (const float*)d_in[2];
    const float* W1 = (const float*)d_in[3];
    const float* b1 = (const float*)d_in[4];
    const float* W2 = (const float*)d_in[5];
    const float* b2 = (const float*)d_in[6];
    float* out = (float*)d_out;

    const int N = in_sizes[0] / 128;     // 100000
    const int E = in_sizes[2];           // 1600000
    const int* src = ei;
    const int* dst = ei + E;
    const int NCB = (N + 511) / 512;     // 196 coarse buckets (<= 256)

    char* ws = (char*)d_ws;
    size_t o = 0;
    ushort* S      = (ushort*)(ws + o); o += (size_t)N * 128 * sizeof(ushort);
    ushort* H1b    = (ushort*)(ws + o); o += (size_t)N * 128 * sizeof(ushort);
    uint2*  ebuf   = (uint2*) (ws + o); o += (size_t)E * sizeof(uint2);
    int2*   csr    = (int2*)  (ws + o); o += ((size_t)E + (size_t)NCB * PADCAP) * sizeof(int2);
    int*    rstart = (int*)   (ws + o); o += (size_t)N * sizeof(int);
    int*    pdeg   = (int*)   (ws + o); o += (size_t)N * sizeof(int);
    int*    chist  = (int*)   (ws + o); o += 256 * sizeof(int);
    int*    cofs   = (int*)   (ws + o); o += 257 * sizeof(int);
    int*    ccur   = (int*)   (ws + o); o += 256 * sizeof(int);
    ushort* Wt1    = (ushort*)(ws + o); o += 128 * 128 * sizeof(ushort);
    ushort* Wt2    = (ushort*)(ws + o); o += 128 * 64 * sizeof(ushort);

    // ---- CSR build (+ fused weight conversion) ----
    hipMemsetAsync(chist, 0, 256 * sizeof(int), stream);
    chist_kernel<<<1024, 256, 0, stream>>>(dst, chist, E, W1, Wt1, W2, Wt2);
    cscan_kernel<<<1, 256, 0, stream>>>(chist, cofs, ccur);
    binA_kernel<<<(E + 4095) / 4096, 256, 0, stream>>>(src, dst, ew, ccur, ebuf, E);
    binB_kernel<<<NCB, 512, 0, stream>>>(ebuf, cofs, rstart, pdeg, csr, N);

    const int GB = (N + 127) / 128;

    // ---- layer 1 ----
    gemm_mfma<128, false><<<GB, 256, 0, stream>>>(x, Wt1, S, N);
    agg_kernel<128, true><<<(N + 3) / 4, 256, 0, stream>>>(S, rstart, pdeg, csr, b1, H1b, N);

    // ---- layer 2 ----
    gemm_mfma<64, true><<<GB, 256, 0, stream>>>(H1b, Wt2, S, N);
    agg_kernel<64, false><<<(N + 3) / 4, 256, 0, stream>>>(S, rstart, pdeg, csr, b2, out, N);
}